// Round 1
// baseline (578.169 us; speedup 1.0000x reference)
//
#include <hip/hip_runtime.h>
#include <math.h>

#define B_   128
#define N1_  128
#define N2_  384
#define N_   512
#define E_   1024
#define DIN  64
#define DFC  128

// workspace layout (floats)
#define ACC_TOP 0
#define ACC_BOT 128
#define RN_OFF  256                       // B*N1 rownorms
#define CN_OFF  (256 + B_*N1_)            // B*N2 colnorms

// ---------------- init ----------------
__global__ void k_init(float* ws, float* out) {
    int t = threadIdx.x;
    if (t < 256) ws[t] = 0.f;
    if (t < 4) out[128 + t] = 0.f;
}

// ---------------- attention norms ----------------
// grid B, block 384
__global__ void k_norms(const float* __restrict__ att, float* __restrict__ ws) {
    int b = blockIdx.x, t = threadIdx.x;
    const float* A = att + (size_t)b * N1_ * N2_;
    float s = 0.f;
    for (int j = 0; j < N1_; ++j) { float v = A[j * N2_ + t]; s += v * v; }
    ws[CN_OFF + b * N2_ + t] = sqrtf(s);
    if (t < N1_) {
        const float* row = A + t * N2_;
        float r = 0.f;
        for (int k = 0; k < N2_; ++k) { float v = row[k]; r += v * v; }
        ws[RN_OFF + b * N1_ + t] = sqrtf(r);
    }
}

// ---------------- scores MLP ----------------
// grid B, block 128
__global__ void k_mlp(const float* __restrict__ c_hs, const float* __restrict__ c_valid,
                      const float* __restrict__ W0, const float* __restrict__ b0,
                      const float* __restrict__ W1, const float* __restrict__ b1,
                      const float* __restrict__ W2, const float* __restrict__ b2,
                      const float* __restrict__ W3, const float* __restrict__ b3,
                      float* __restrict__ out) {
    __shared__ float pool[DIN];
    __shared__ float part[DFC];
    __shared__ float h[DFC];
    __shared__ float h2[DFC];
    int b = blockIdx.x, t = threadIdx.x;
    int d = t & 63, half = t >> 6;
    const float* X = c_hs + (size_t)b * N_ * DIN;
    const float* V = c_valid + (size_t)b * N_;
    float s = 0.f;
    for (int n = half; n < N_; n += 2) s += X[n * DIN + d] * V[n];
    part[t] = s; __syncthreads();
    if (t < DIN) pool[t] = (part[t] + part[t + 64]) * (1.0f / 128.0f);
    __syncthreads();
    float a = b0[t];
    for (int i = 0; i < DIN; ++i) a += pool[i] * W0[i * DFC + t];
    h[t] = fmaxf(a, 0.f); __syncthreads();
    a = b1[t];
    for (int i = 0; i < DFC; ++i) a += h[i] * W1[i * DFC + t];
    h2[t] = fmaxf(a, 0.f); __syncthreads();
    a = b2[t];
    for (int i = 0; i < DFC; ++i) a += h2[i] * W2[i * DFC + t];
    __syncthreads();            // h reads in layer1 are done
    h[t] = fmaxf(a, 0.f);
    part[t] = fmaxf(a, 0.f) * W3[t];
    __syncthreads();
    for (int off = 64; off > 0; off >>= 1) { if (t < off) part[t] += part[t + off]; __syncthreads(); }
    if (t == 0) out[b] = 1.f / (1.f + expf(-(part[0] + b3[0])));
}

// ---------------- mask scan: rows i in [0,128) ----------------
// grid (128, B), block 256
__global__ void k_maskA(const float* __restrict__ att, const float* __restrict__ mapping,
                        const float* __restrict__ samelb, const float* __restrict__ ws) {
    __shared__ float w[N2_];
    __shared__ float rt[4], rb[4];
    int b = blockIdx.y, i = blockIdx.x, t = threadIdx.x;
    const float* cn = ws + CN_OFF + b * N2_;
    const float* row = att + ((size_t)b * N1_ + i) * N2_;
    for (int j = t; j < N2_; j += 256)
        w[j] = row[j] / fmaxf(cn[j], 1e-12f);
    __syncthreads();
    size_t base = ((size_t)b * N_ + i) * N_;
    float top = 0.f, bot = 0.f;
    for (int j = t; j < N_; j += 256) {
        float m = mapping[base + j], sl = samelb[base + j];
        float e = (j < N1_) ? 1.0f : __expf(-w[j - N1_]);
        if (m == 1.0f) top += e;
        if (sl == 1.0f) bot += e;
    }
    for (int off = 32; off > 0; off >>= 1) {
        top += __shfl_down(top, off, 64);
        bot += __shfl_down(bot, off, 64);
    }
    int wv = t >> 6, ln = t & 63;
    if (ln == 0) { rt[wv] = top; rb[wv] = bot; }
    __syncthreads();
    if (t == 0) {
        float* wsw = (float*)ws;
        atomicAdd(&wsw[ACC_TOP + b], rt[0] + rt[1] + rt[2] + rt[3]);
        atomicAdd(&wsw[ACC_BOT + b], rb[0] + rb[1] + rb[2] + rb[3]);
    }
}

// ---------------- mask scan: rows i in [128,512), 32-row tiles ----------------
// grid (12, B), block 256
__global__ void k_maskB(const float* __restrict__ att, const float* __restrict__ mapping,
                        const float* __restrict__ samelb, const float* __restrict__ ws) {
    __shared__ float rinv[N1_];
    __shared__ float tile[32 * 129];
    __shared__ float rt[4], rb[4];
    int b = blockIdx.y, tbl = blockIdx.x, t = threadIdx.x;
    int k0 = tbl * 32;
    if (t < N1_) rinv[t] = 1.f / fmaxf(ws[RN_OFF + b * N1_ + t], 1e-12f);
    __syncthreads();
    int kk = t & 31, jj = t >> 5;
    for (int j = jj; j < N1_; j += 8)
        tile[kk * 129 + j] = att[((size_t)b * N1_ + j) * N2_ + k0 + kk] * rinv[j];
    __syncthreads();
    float top = 0.f, bot = 0.f;
    for (int r = 0; r < 32; ++r) {
        int i = N1_ + k0 + r;
        size_t base = ((size_t)b * N_ + i) * N_;
        const float* trow = &tile[r * 129];
        for (int j = t; j < N_; j += 256) {
            float m = mapping[base + j], sl = samelb[base + j];
            float e = (j < N1_) ? __expf(-trow[j]) : 1.0f;
            if (m == 1.0f) top += e;
            if (sl == 1.0f) bot += e;
        }
    }
    for (int off = 32; off > 0; off >>= 1) {
        top += __shfl_down(top, off, 64);
        bot += __shfl_down(bot, off, 64);
    }
    int wv = t >> 6, ln = t & 63;
    if (ln == 0) { rt[wv] = top; rb[wv] = bot; }
    __syncthreads();
    if (t == 0) {
        float* wsw = (float*)ws;
        atomicAdd(&wsw[ACC_TOP + b], rt[0] + rt[1] + rt[2] + rt[3]);
        atomicAdd(&wsw[ACC_BOT + b], rb[0] + rb[1] + rb[2] + rb[3]);
    }
}

// ---------------- attn_loss finalize ----------------
__global__ void k_attnfin(const float* __restrict__ ws, float* __restrict__ out) {
    __shared__ float red[128];
    int t = threadIdx.x;
    float top = ws[ACC_TOP + t], bot = ws[ACC_BOT + t];
    red[t] = top / (bot - top + 1.0f);
    __syncthreads();
    for (int off = 64; off > 0; off >>= 1) { if (t < off) red[t] += red[t + off]; __syncthreads(); }
    if (t == 0) out[128] = red[0] * (1.0f / 128.0f);   // THETA=1, /B
}

// ---------------- Kabsch ----------------
__device__ inline float bred(float* s, float v, int t) {
    __syncthreads();
    s[t] = v; __syncthreads();
    for (int off = 64; off > 0; off >>= 1) { if (t < off) s[t] += s[t + off]; __syncthreads(); }
    float r = s[0]; __syncthreads(); return r;
}

// grid B, block 128
__global__ void k_kabsch(const float* __restrict__ att, const float* __restrict__ coords,
                         const float* __restrict__ upd, const float* __restrict__ nm,
                         float* __restrict__ out) {
    __shared__ float sred[128];
    __shared__ float Rsh[9], Tsh[3];
    int b = blockIdx.x, t = threadIdx.x;
    // argmax over attention row t (first-max, like jnp.argmax)
    const float* arow = att + ((size_t)b * N1_ + t) * N2_;
    float best = arow[0]; int bi = 0;
    for (int k = 1; k < N2_; ++k) { float v = arow[k]; if (v > best) { best = v; bi = k; } }
    float P[3], Q[3];
    const float* up = upd + ((size_t)b * N_ + t) * 3;
    P[0] = up[0]; P[1] = up[1]; P[2] = up[2];
    const float* qp = coords + ((size_t)b * N_ + N1_ + bi) * 3;
    Q[0] = qp[0]; Q[1] = qp[1]; Q[2] = qp[2];
    float Pm[3], Qm[3];
    for (int a = 0; a < 3; ++a) Pm[a] = bred(sred, P[a], t) * (1.f / 128.f);
    for (int a = 0; a < 3; ++a) Qm[a] = bred(sred, Q[a], t) * (1.f / 128.f);
    float H[9];
    for (int a = 0; a < 3; ++a)
        for (int c = 0; c < 3; ++c)
            H[a * 3 + c] = bred(sred, (P[a] - Pm[a]) * (Q[c] - Qm[c]), t) * (1.f / 8.f);
    if (t == 0) {
        double Hd[3][3];
        for (int a = 0; a < 3; ++a) for (int c = 0; c < 3; ++c) Hd[a][c] = (double)H[a * 3 + c];
        // A = H^T H
        double A[3][3], V[3][3] = {{1,0,0},{0,1,0},{0,0,1}};
        for (int i = 0; i < 3; ++i)
            for (int j = 0; j < 3; ++j) {
                double s2 = 0; for (int c = 0; c < 3; ++c) s2 += Hd[c][i] * Hd[c][j];
                A[i][j] = s2;
            }
        for (int sweep = 0; sweep < 12; ++sweep) {
            const int PQ[3][2] = {{0,1},{0,2},{1,2}};
            for (int r = 0; r < 3; ++r) {
                int p = PQ[r][0], q = PQ[r][1];
                double apq = A[p][q];
                if (fabs(apq) < 1e-300) continue;
                double tau = (A[q][q] - A[p][p]) / (2.0 * apq);
                double tt = (tau >= 0 ? 1.0 : -1.0) / (fabs(tau) + sqrt(1.0 + tau * tau));
                double c = 1.0 / sqrt(1.0 + tt * tt), s = tt * c;
                for (int k = 0; k < 3; ++k) { double akp = A[k][p], akq = A[k][q]; A[k][p] = c * akp - s * akq; A[k][q] = s * akp + c * akq; }
                for (int k = 0; k < 3; ++k) { double apk = A[p][k], aqk = A[q][k]; A[p][k] = c * apk - s * aqk; A[q][k] = s * apk + c * aqk; }
                for (int k = 0; k < 3; ++k) { double vkp = V[k][p], vkq = V[k][q]; V[k][p] = c * vkp - s * vkq; V[k][q] = s * vkp + c * vkq; }
            }
        }
        double lam[3] = {A[0][0], A[1][1], A[2][2]};
        int id[3] = {0, 1, 2};
        if (lam[id[0]] < lam[id[1]]) { int x = id[0]; id[0] = id[1]; id[1] = x; }
        if (lam[id[0]] < lam[id[2]]) { int x = id[0]; id[0] = id[2]; id[2] = x; }
        if (lam[id[1]] < lam[id[2]]) { int x = id[1]; id[1] = id[2]; id[2] = x; }
        double u[3][3], v[3][3], sv[3];
        for (int i = 0; i < 3; ++i) {
            for (int k = 0; k < 3; ++k) v[i][k] = V[k][id[i]];
            double uv[3];
            for (int c = 0; c < 3; ++c) uv[c] = Hd[c][0] * v[i][0] + Hd[c][1] * v[i][1] + Hd[c][2] * v[i][2];
            double n = sqrt(uv[0] * uv[0] + uv[1] * uv[1] + uv[2] * uv[2]);
            sv[i] = n;
            if (n > 1e-150) { u[i][0] = uv[0] / n; u[i][1] = uv[1] / n; u[i][2] = uv[2] / n; }
            else { u[i][0] = u[i][1] = u[i][2] = 0.0; }
        }
        if (sv[2] < 1e-12 * fmax(sv[0], 1e-300)) {   // degenerate fallback
            u[2][0] = u[0][1] * u[1][2] - u[0][2] * u[1][1];
            u[2][1] = u[0][2] * u[1][0] - u[0][0] * u[1][2];
            u[2][2] = u[0][0] * u[1][1] - u[0][1] * u[1][0];
        }
        double det = Hd[0][0] * (Hd[1][1] * Hd[2][2] - Hd[1][2] * Hd[2][1])
                   - Hd[0][1] * (Hd[1][0] * Hd[2][2] - Hd[1][2] * Hd[2][0])
                   + Hd[0][2] * (Hd[1][0] * Hd[2][1] - Hd[1][1] * Hd[2][0]);
        double dsg = (det > 0.0) ? 1.0 : ((det < 0.0) ? -1.0 : 0.0);
        for (int a = 0; a < 3; ++a)
            for (int c = 0; c < 3; ++c)
                Rsh[a * 3 + c] = (float)(u[0][a] * v[0][c] + u[1][a] * v[1][c] + dsg * u[2][a] * v[2][c]);
        for (int a = 0; a < 3; ++a)
            Tsh[a] = Qm[a] - (Rsh[a * 3] * Pm[0] + Rsh[a * 3 + 1] * Pm[1] + Rsh[a * 3 + 2] * Pm[2]);
    }
    __syncthreads();
    float Pp[3];
    for (int a = 0; a < 3; ++a)
        Pp[a] = Rsh[a * 3] * P[0] + Rsh[a * 3 + 1] * P[1] + Rsh[a * 3 + 2] * P[2] + Tsh[a];
    float mk = (nm[b * N1_ + t] > 0.5f) ? 1.f : 0.f;
    float dx = Pp[0] - Q[0], dy = Pp[1] - Q[1], dz = Pp[2] - Q[2];
    float rsum = bred(sred, mk * (dx * dx + dy * dy + dz * dz), t);
    float msum = bred(sred, mk, t);
    float Ppm[3];
    for (int a = 0; a < 3; ++a) Ppm[a] = bred(sred, Pp[a], t) * (1.f / 128.f);
    if (t == 0) {
        float cnt = fmaxf(msum * 3.f, 1.f);
        atomicAdd(&out[129], (rsum / cnt) * (1.f / 128.f));
        float cen = 0.f;
        for (int a = 0; a < 3; ++a) { float d2 = Ppm[a] - Qm[a]; cen += d2 * d2; }
        atomicAdd(&out[131], (cen / 3.f) * (1.f / 128.f));
    }
}

// ---------------- pairdst ----------------
// grid B, block 256
__global__ void k_pair(const float* __restrict__ coords, const float* __restrict__ upd,
                       const int* __restrict__ ei, float* __restrict__ out) {
    __shared__ float rw[4];
    int b = blockIdx.x, t = threadIdx.x;
    const float* C = coords + (size_t)b * N_ * 3;
    const float* U = upd + (size_t)b * N_ * 3;
    const int* e = ei + (size_t)b * E_ * 2;
    float acc = 0.f;
    for (int idx = t; idx < E_; idx += 256) {
        int a0 = e[idx * 2], a1 = e[idx * 2 + 1];
        float dx = C[a0 * 3] - C[a1 * 3], dy = C[a0 * 3 + 1] - C[a1 * 3 + 1], dz = C[a0 * 3 + 2] - C[a1 * 3 + 2];
        float d0 = sqrtf(dx * dx + dy * dy + dz * dz + 1e-12f);
        dx = U[a0 * 3] - U[a1 * 3]; dy = U[a0 * 3 + 1] - U[a1 * 3 + 1]; dz = U[a0 * 3 + 2] - U[a1 * 3 + 2];
        float d1 = sqrtf(dx * dx + dy * dy + dz * dz + 1e-12f);
        acc += d1 - d0;
    }
    for (int off = 32; off > 0; off >>= 1) acc += __shfl_down(acc, off, 64);
    int wv = t >> 6, ln = t & 63;
    if (ln == 0) rw[wv] = acc;
    __syncthreads();
    if (t == 0) atomicAdd(&out[130], fabsf(rw[0] + rw[1] + rw[2] + rw[3]) * (1.f / 128.f));
}

extern "C" void kernel_launch(void* const* d_in, const int* in_sizes, int n_in,
                              void* d_out, int out_size, void* d_ws, size_t ws_size,
                              hipStream_t stream) {
    const float* c_hs      = (const float*)d_in[0];
    const float* attention = (const float*)d_in[1];
    const float* coords    = (const float*)d_in[2];
    const float* upd       = (const float*)d_in[3];
    const float* c_valid   = (const float*)d_in[4];
    const float* nm        = (const float*)d_in[5];
    const float* mapping   = (const float*)d_in[6];
    const float* samelb    = (const float*)d_in[7];
    const int*   ei        = (const int*)d_in[8];
    const float* W0 = (const float*)d_in[9],  *b0 = (const float*)d_in[10];
    const float* W1 = (const float*)d_in[11], *b1 = (const float*)d_in[12];
    const float* W2 = (const float*)d_in[13], *b2 = (const float*)d_in[14];
    const float* W3 = (const float*)d_in[15], *b3 = (const float*)d_in[16];
    float* out = (float*)d_out;
    float* ws  = (float*)d_ws;

    hipLaunchKernelGGL(k_init,    dim3(1),        dim3(256), 0, stream, ws, out);
    hipLaunchKernelGGL(k_norms,   dim3(B_),       dim3(N2_), 0, stream, attention, ws);
    hipLaunchKernelGGL(k_mlp,     dim3(B_),       dim3(DFC), 0, stream, c_hs, c_valid,
                       W0, b0, W1, b1, W2, b2, W3, b3, out);
    hipLaunchKernelGGL(k_maskA,   dim3(N1_, B_),  dim3(256), 0, stream, attention, mapping, samelb, ws);
    hipLaunchKernelGGL(k_maskB,   dim3(12, B_),   dim3(256), 0, stream, attention, mapping, samelb, ws);
    hipLaunchKernelGGL(k_attnfin, dim3(1),        dim3(128), 0, stream, ws, out);
    hipLaunchKernelGGL(k_kabsch,  dim3(B_),       dim3(N1_), 0, stream, attention, coords, upd, nm, out);
    hipLaunchKernelGGL(k_pair,    dim3(B_),       dim3(256), 0, stream, coords, upd, ei, out);
}

// Round 2
// 456.488 us; speedup vs baseline: 1.2666x; 1.2666x over previous
//
#include <hip/hip_runtime.h>
#include <math.h>

#define B_   128
#define N1_  128
#define N2_  384
#define N_   512
#define E_   1024
#define DIN  64
#define DFC  128

// workspace layout (floats)
#define ACC_TOP  0
#define ACC_BOT  128
#define POOL_OFF 256                        // B*64
#define RN_OFF   (256 + B_*DIN)             // B*N1 rownorms
#define CN_OFF   (RN_OFF + B_*N1_)          // B*N2 colnorms
#define ZERO_CNT (256 + B_*DIN)             // floats to zero (acc + pool)

// ---------------- init ----------------
// grid 33, block 256
__global__ void k_init(float* ws, float* out) {
    int idx = blockIdx.x * 256 + threadIdx.x;
    if (idx < ZERO_CNT) ws[idx] = 0.f;
    if (blockIdx.x == 0 && threadIdx.x < 4) out[128 + threadIdx.x] = 0.f;
}

// ---------------- masked mean-pool ----------------
// grid (B, 4), block 256. Each block: 128 rows of N.
__global__ void k_pool(const float* __restrict__ c_hs, const float* __restrict__ c_valid,
                       float* __restrict__ ws) {
    __shared__ float4 sred[256];
    int b = blockIdx.x, t = threadIdx.x;
    int chunk = blockIdx.y * 128;
    int d4 = t & 15, rl = t >> 4;
    const float4* X4 = (const float4*)(c_hs + (size_t)b * N_ * DIN);
    const float* V = c_valid + (size_t)b * N_;
    float4 acc = {0.f, 0.f, 0.f, 0.f};
    for (int r = chunk + rl; r < chunk + 128; r += 16) {
        float4 x = X4[r * 16 + d4];
        float v = V[r];
        acc.x += x.x * v; acc.y += x.y * v; acc.z += x.z * v; acc.w += x.w * v;
    }
    sred[t] = acc; __syncthreads();
    for (int off = 128; off >= 16; off >>= 1) {
        if (t < off) {
            float4 o = sred[t + off];
            sred[t].x += o.x; sred[t].y += o.y; sred[t].z += o.z; sred[t].w += o.w;
        }
        __syncthreads();
    }
    if (t < 16) {
        float4 s = sred[t];
        float* p = ws + POOL_OFF + b * DIN + t * 4;
        atomicAdd(&p[0], s.x); atomicAdd(&p[1], s.y);
        atomicAdd(&p[2], s.z); atomicAdd(&p[3], s.w);
    }
}

// ---------------- scores MLP (pooled already in ws) ----------------
// grid B, block 128
__global__ void k_mlp2(const float* __restrict__ ws,
                       const float* __restrict__ W0, const float* __restrict__ b0,
                       const float* __restrict__ W1, const float* __restrict__ b1,
                       const float* __restrict__ W2, const float* __restrict__ b2,
                       const float* __restrict__ W3, const float* __restrict__ b3,
                       float* __restrict__ out) {
    __shared__ float pool[DIN];
    __shared__ float h[DFC];
    __shared__ float h2[DFC];
    __shared__ float part[DFC];
    int b = blockIdx.x, t = threadIdx.x;
    if (t < DIN) pool[t] = ws[POOL_OFF + b * DIN + t] * (1.0f / 128.0f);
    __syncthreads();
    float a = b0[t];
    for (int i = 0; i < DIN; ++i) a += pool[i] * W0[i * DFC + t];
    h[t] = fmaxf(a, 0.f); __syncthreads();
    a = b1[t];
    for (int i = 0; i < DFC; ++i) a += h[i] * W1[i * DFC + t];
    h2[t] = fmaxf(a, 0.f); __syncthreads();
    a = b2[t];
    for (int i = 0; i < DFC; ++i) a += h2[i] * W2[i * DFC + t];
    part[t] = fmaxf(a, 0.f) * W3[t];
    __syncthreads();
    for (int off = 64; off > 0; off >>= 1) { if (t < off) part[t] += part[t + off]; __syncthreads(); }
    if (t == 0) out[b] = 1.f / (1.f + expf(-(part[0] + b3[0])));
}

// ---------------- attention norms ----------------
// grid B, block 512
__global__ void k_norms(const float* __restrict__ att, float* __restrict__ ws) {
    int b = blockIdx.x, t = threadIdx.x;
    const float* A = att + (size_t)b * N1_ * N2_;
    // column norms: threads 0..383, coalesced down rows
    if (t < N2_) {
        float s = 0.f;
        for (int j = 0; j < N1_; ++j) { float v = A[j * N2_ + t]; s += v * v; }
        ws[CN_OFF + b * N2_ + t] = sqrtf(s);
    }
    // row norms: one wave per row-group (8 waves x 16 rows), lane-coalesced
    int wv = t >> 6, ln = t & 63;
    for (int r = wv * 16; r < wv * 16 + 16; ++r) {
        const float* row = A + r * N2_;
        float s = 0.f;
        for (int q = 0; q < 6; ++q) { float v = row[ln + 64 * q]; s += v * v; }
        for (int off = 32; off > 0; off >>= 1) s += __shfl_down(s, off, 64);
        if (ln == 0) ws[RN_OFF + b * N1_ + r] = sqrtf(s);
    }
}

// ---------------- mask scan: rows i in [0,128), 16 rows/block ----------------
// grid (8, B), block 256
__global__ void k_maskA(const float* __restrict__ att, const float* __restrict__ mapping,
                        const float* __restrict__ samelb, float* __restrict__ ws) {
    __shared__ float cninv[N2_];
    __shared__ float w2[2 * N2_];
    __shared__ float rt[4], rb[4];
    int b = blockIdx.y, t = threadIdx.x;
    int i0 = blockIdx.x * 16;
    for (int j = t; j < N2_; j += 256)
        cninv[j] = 1.f / fmaxf(ws[CN_OFF + b * N2_ + j], 1e-12f);
    int half = t >> 7, tl = t & 127;
    float top = 0.f, bot = 0.f;
    for (int p = 0; p < 8; ++p) {
        __syncthreads();                       // covers cninv on p==0, w2 reuse after
        // rows i0+2p, i0+2p+1 are contiguous: 768 floats
        const float* src = att + ((size_t)(b * N1_ + i0 + 2 * p)) * N2_;
        for (int j = t; j < 2 * N2_; j += 256) {
            int col = (j >= N2_) ? (j - N2_) : j;
            w2[j] = src[j] * cninv[col];
        }
        __syncthreads();
        int i = i0 + 2 * p + half;
        const float4* m4 = (const float4*)(mapping + ((size_t)(b * N_ + i)) * N_);
        const float4* s4 = (const float4*)(samelb + ((size_t)(b * N_ + i)) * N_);
        float4 mv = m4[tl], sv = s4[tl];
        if (tl < 32) {                          // j in [0,128): atten==0, e=1
            top += (mv.x == 1.f ? 1.f : 0.f) + (mv.y == 1.f ? 1.f : 0.f)
                 + (mv.z == 1.f ? 1.f : 0.f) + (mv.w == 1.f ? 1.f : 0.f);
            bot += (sv.x == 1.f ? 1.f : 0.f) + (sv.y == 1.f ? 1.f : 0.f)
                 + (sv.z == 1.f ? 1.f : 0.f) + (sv.w == 1.f ? 1.f : 0.f);
        } else {
            int jj = half * N2_ + tl * 4 - N1_;
            float e0 = __expf(-w2[jj]),     e1 = __expf(-w2[jj + 1]);
            float e2 = __expf(-w2[jj + 2]), e3 = __expf(-w2[jj + 3]);
            top += (mv.x == 1.f ? e0 : 0.f) + (mv.y == 1.f ? e1 : 0.f)
                 + (mv.z == 1.f ? e2 : 0.f) + (mv.w == 1.f ? e3 : 0.f);
            bot += (sv.x == 1.f ? e0 : 0.f) + (sv.y == 1.f ? e1 : 0.f)
                 + (sv.z == 1.f ? e2 : 0.f) + (sv.w == 1.f ? e3 : 0.f);
        }
    }
    for (int off = 32; off > 0; off >>= 1) {
        top += __shfl_down(top, off, 64);
        bot += __shfl_down(bot, off, 64);
    }
    int wv = t >> 6, ln = t & 63;
    if (ln == 0) { rt[wv] = top; rb[wv] = bot; }
    __syncthreads();
    if (t == 0) {
        atomicAdd(&ws[ACC_TOP + b], rt[0] + rt[1] + rt[2] + rt[3]);
        atomicAdd(&ws[ACC_BOT + b], rb[0] + rb[1] + rb[2] + rb[3]);
    }
}

// ---------------- mask scan: rows i in [128,512), 16-row tiles ----------------
// grid (24, B), block 256
#define TSTR 132
__global__ void k_maskB(const float* __restrict__ att, const float* __restrict__ mapping,
                        const float* __restrict__ samelb, float* __restrict__ ws) {
    __shared__ float rinv[N1_];
    __shared__ float tile[16 * TSTR];
    __shared__ float rt[4], rb[4];
    int b = blockIdx.y, t = threadIdx.x;
    int k0 = blockIdx.x * 16;
    if (t < N1_) rinv[t] = 1.f / fmaxf(ws[RN_OFF + b * N1_ + t], 1e-12f);
    __syncthreads();
    // transpose-load: tile[r][j] = att[j, k0+r] * rinv[j]
    int r4 = t & 3;
    for (int j = (t >> 2); j < N1_; j += 64) {
        float4 a = *(const float4*)&att[((size_t)(b * N1_ + j)) * N2_ + k0 + r4 * 4];
        float rv = rinv[j];
        tile[(r4 * 4 + 0) * TSTR + j] = a.x * rv;
        tile[(r4 * 4 + 1) * TSTR + j] = a.y * rv;
        tile[(r4 * 4 + 2) * TSTR + j] = a.z * rv;
        tile[(r4 * 4 + 3) * TSTR + j] = a.w * rv;
    }
    __syncthreads();
    int half = t >> 7, tl = t & 127;
    float top = 0.f, bot = 0.f;
    for (int rp = 0; rp < 8; ++rp) {
        int r = 2 * rp + half;
        int i = N1_ + k0 + r;
        const float4* m4 = (const float4*)(mapping + ((size_t)(b * N_ + i)) * N_);
        const float4* s4 = (const float4*)(samelb + ((size_t)(b * N_ + i)) * N_);
        float4 mv = m4[tl], sv = s4[tl];
        if (tl < 32) {                          // j in [0,128): e = exp(-tile)
            int jj = r * TSTR + tl * 4;
            float e0 = __expf(-tile[jj]),     e1 = __expf(-tile[jj + 1]);
            float e2 = __expf(-tile[jj + 2]), e3 = __expf(-tile[jj + 3]);
            top += (mv.x == 1.f ? e0 : 0.f) + (mv.y == 1.f ? e1 : 0.f)
                 + (mv.z == 1.f ? e2 : 0.f) + (mv.w == 1.f ? e3 : 0.f);
            bot += (sv.x == 1.f ? e0 : 0.f) + (sv.y == 1.f ? e1 : 0.f)
                 + (sv.z == 1.f ? e2 : 0.f) + (sv.w == 1.f ? e3 : 0.f);
        } else {                                // j >= 128: atten==0, e=1
            top += (mv.x == 1.f ? 1.f : 0.f) + (mv.y == 1.f ? 1.f : 0.f)
                 + (mv.z == 1.f ? 1.f : 0.f) + (mv.w == 1.f ? 1.f : 0.f);
            bot += (sv.x == 1.f ? 1.f : 0.f) + (sv.y == 1.f ? 1.f : 0.f)
                 + (sv.z == 1.f ? 1.f : 0.f) + (sv.w == 1.f ? 1.f : 0.f);
        }
    }
    for (int off = 32; off > 0; off >>= 1) {
        top += __shfl_down(top, off, 64);
        bot += __shfl_down(bot, off, 64);
    }
    int wv = t >> 6, ln = t & 63;
    if (ln == 0) { rt[wv] = top; rb[wv] = bot; }
    __syncthreads();
    if (t == 0) {
        atomicAdd(&ws[ACC_TOP + b], rt[0] + rt[1] + rt[2] + rt[3]);
        atomicAdd(&ws[ACC_BOT + b], rb[0] + rb[1] + rb[2] + rb[3]);
    }
}

// ---------------- attn_loss finalize ----------------
__global__ void k_attnfin(const float* __restrict__ ws, float* __restrict__ out) {
    __shared__ float red[128];
    int t = threadIdx.x;
    float top = ws[ACC_TOP + t], bot = ws[ACC_BOT + t];
    red[t] = top / (bot - top + 1.0f);
    __syncthreads();
    for (int off = 64; off > 0; off >>= 1) { if (t < off) red[t] += red[t + off]; __syncthreads(); }
    if (t == 0) out[128] = red[0] * (1.0f / 128.0f);   // THETA=1, /B
}

// ---------------- Kabsch ----------------
__device__ inline float bred(float* s, float v, int t) {
    __syncthreads();
    s[t] = v; __syncthreads();
    for (int off = 64; off > 0; off >>= 1) { if (t < off) s[t] += s[t + off]; __syncthreads(); }
    float r = s[0]; __syncthreads(); return r;
}

// grid B, block 128
__global__ void k_kabsch(const float* __restrict__ att, const float* __restrict__ coords,
                         const float* __restrict__ upd, const float* __restrict__ nm,
                         float* __restrict__ out) {
    __shared__ float sred[128];
    __shared__ float Rsh[9], Tsh[3];
    __shared__ int bi[N1_];
    int b = blockIdx.x, t = threadIdx.x;
    int wv = t >> 6, ln = t & 63;
    // wave-cooperative argmax per row (first-max semantics)
    for (int r = wv * 64; r < wv * 64 + 64; ++r) {
        const float* arow = att + ((size_t)b * N1_ + r) * N2_;
        float best = -1e30f; int bidx = 0;
        for (int q = 0; q < 6; ++q) {
            float v = arow[ln + 64 * q];
            if (v > best) { best = v; bidx = ln + 64 * q; }   // ascending idx: > keeps first
        }
        for (int off = 32; off > 0; off >>= 1) {
            float ov = __shfl_xor(best, off, 64);
            int oi = __shfl_xor(bidx, off, 64);
            if (ov > best || (ov == best && oi < bidx)) { best = ov; bidx = oi; }
        }
        if (ln == 0) bi[r] = bidx;
    }
    __syncthreads();
    float P[3], Q[3];
    const float* up = upd + ((size_t)b * N_ + t) * 3;
    P[0] = up[0]; P[1] = up[1]; P[2] = up[2];
    const float* qp = coords + ((size_t)b * N_ + N1_ + bi[t]) * 3;
    Q[0] = qp[0]; Q[1] = qp[1]; Q[2] = qp[2];
    float Pm[3], Qm[3];
    for (int a = 0; a < 3; ++a) Pm[a] = bred(sred, P[a], t) * (1.f / 128.f);
    for (int a = 0; a < 3; ++a) Qm[a] = bred(sred, Q[a], t) * (1.f / 128.f);
    float H[9];
    for (int a = 0; a < 3; ++a)
        for (int c = 0; c < 3; ++c)
            H[a * 3 + c] = bred(sred, (P[a] - Pm[a]) * (Q[c] - Qm[c]), t) * (1.f / 8.f);
    if (t == 0) {
        double Hd[3][3];
        for (int a = 0; a < 3; ++a) for (int c = 0; c < 3; ++c) Hd[a][c] = (double)H[a * 3 + c];
        double A[3][3], V[3][3] = {{1,0,0},{0,1,0},{0,0,1}};
        for (int i = 0; i < 3; ++i)
            for (int j = 0; j < 3; ++j) {
                double s2 = 0; for (int c = 0; c < 3; ++c) s2 += Hd[c][i] * Hd[c][j];
                A[i][j] = s2;
            }
        for (int sweep = 0; sweep < 12; ++sweep) {
            const int PQ[3][2] = {{0,1},{0,2},{1,2}};
            for (int r = 0; r < 3; ++r) {
                int p = PQ[r][0], q = PQ[r][1];
                double apq = A[p][q];
                if (fabs(apq) < 1e-300) continue;
                double tau = (A[q][q] - A[p][p]) / (2.0 * apq);
                double tt = (tau >= 0 ? 1.0 : -1.0) / (fabs(tau) + sqrt(1.0 + tau * tau));
                double c = 1.0 / sqrt(1.0 + tt * tt), s = tt * c;
                for (int k = 0; k < 3; ++k) { double akp = A[k][p], akq = A[k][q]; A[k][p] = c * akp - s * akq; A[k][q] = s * akp + c * akq; }
                for (int k = 0; k < 3; ++k) { double apk = A[p][k], aqk = A[q][k]; A[p][k] = c * apk - s * aqk; A[q][k] = s * apk + c * aqk; }
                for (int k = 0; k < 3; ++k) { double vkp = V[k][p], vkq = V[k][q]; V[k][p] = c * vkp - s * vkq; V[k][q] = s * vkp + c * vkq; }
            }
        }
        double lam[3] = {A[0][0], A[1][1], A[2][2]};
        int id[3] = {0, 1, 2};
        if (lam[id[0]] < lam[id[1]]) { int x = id[0]; id[0] = id[1]; id[1] = x; }
        if (lam[id[0]] < lam[id[2]]) { int x = id[0]; id[0] = id[2]; id[2] = x; }
        if (lam[id[1]] < lam[id[2]]) { int x = id[1]; id[1] = id[2]; id[2] = x; }
        double u[3][3], v[3][3], sv[3];
        for (int i = 0; i < 3; ++i) {
            for (int k = 0; k < 3; ++k) v[i][k] = V[k][id[i]];
            double uv[3];
            for (int c = 0; c < 3; ++c) uv[c] = Hd[c][0] * v[i][0] + Hd[c][1] * v[i][1] + Hd[c][2] * v[i][2];
            double n = sqrt(uv[0] * uv[0] + uv[1] * uv[1] + uv[2] * uv[2]);
            sv[i] = n;
            if (n > 1e-150) { u[i][0] = uv[0] / n; u[i][1] = uv[1] / n; u[i][2] = uv[2] / n; }
            else { u[i][0] = u[i][1] = u[i][2] = 0.0; }
        }
        if (sv[2] < 1e-12 * fmax(sv[0], 1e-300)) {
            u[2][0] = u[0][1] * u[1][2] - u[0][2] * u[1][1];
            u[2][1] = u[0][2] * u[1][0] - u[0][0] * u[1][2];
            u[2][2] = u[0][0] * u[1][1] - u[0][1] * u[1][0];
        }
        double det = Hd[0][0] * (Hd[1][1] * Hd[2][2] - Hd[1][2] * Hd[2][1])
                   - Hd[0][1] * (Hd[1][0] * Hd[2][2] - Hd[1][2] * Hd[2][0])
                   + Hd[0][2] * (Hd[1][0] * Hd[2][1] - Hd[1][1] * Hd[2][0]);
        double dsg = (det > 0.0) ? 1.0 : ((det < 0.0) ? -1.0 : 0.0);
        for (int a = 0; a < 3; ++a)
            for (int c = 0; c < 3; ++c)
                Rsh[a * 3 + c] = (float)(u[0][a] * v[0][c] + u[1][a] * v[1][c] + dsg * u[2][a] * v[2][c]);
        for (int a = 0; a < 3; ++a)
            Tsh[a] = Qm[a] - (Rsh[a * 3] * Pm[0] + Rsh[a * 3 + 1] * Pm[1] + Rsh[a * 3 + 2] * Pm[2]);
    }
    __syncthreads();
    float Pp[3];
    for (int a = 0; a < 3; ++a)
        Pp[a] = Rsh[a * 3] * P[0] + Rsh[a * 3 + 1] * P[1] + Rsh[a * 3 + 2] * P[2] + Tsh[a];
    float mk = (nm[b * N1_ + t] > 0.5f) ? 1.f : 0.f;
    float dx = Pp[0] - Q[0], dy = Pp[1] - Q[1], dz = Pp[2] - Q[2];
    float rsum = bred(sred, mk * (dx * dx + dy * dy + dz * dz), t);
    float msum = bred(sred, mk, t);
    float Ppm[3];
    for (int a = 0; a < 3; ++a) Ppm[a] = bred(sred, Pp[a], t) * (1.f / 128.f);
    if (t == 0) {
        float cnt = fmaxf(msum * 3.f, 1.f);
        atomicAdd(&out[129], (rsum / cnt) * (1.f / 128.f));
        float cen = 0.f;
        for (int a = 0; a < 3; ++a) { float d2 = Ppm[a] - Qm[a]; cen += d2 * d2; }
        atomicAdd(&out[131], (cen / 3.f) * (1.f / 128.f));
    }
}

// ---------------- pairdst ----------------
// grid B, block 256
__global__ void k_pair(const float* __restrict__ coords, const float* __restrict__ upd,
                       const int* __restrict__ ei, float* __restrict__ out) {
    __shared__ float rw[4];
    int b = blockIdx.x, t = threadIdx.x;
    const float* C = coords + (size_t)b * N_ * 3;
    const float* U = upd + (size_t)b * N_ * 3;
    const int* e = ei + (size_t)b * E_ * 2;
    float acc = 0.f;
    for (int idx = t; idx < E_; idx += 256) {
        int a0 = e[idx * 2], a1 = e[idx * 2 + 1];
        float dx = C[a0 * 3] - C[a1 * 3], dy = C[a0 * 3 + 1] - C[a1 * 3 + 1], dz = C[a0 * 3 + 2] - C[a1 * 3 + 2];
        float d0 = sqrtf(dx * dx + dy * dy + dz * dz + 1e-12f);
        dx = U[a0 * 3] - U[a1 * 3]; dy = U[a0 * 3 + 1] - U[a1 * 3 + 1]; dz = U[a0 * 3 + 2] - U[a1 * 3 + 2];
        float d1 = sqrtf(dx * dx + dy * dy + dz * dz + 1e-12f);
        acc += d1 - d0;
    }
    for (int off = 32; off > 0; off >>= 1) acc += __shfl_down(acc, off, 64);
    int wv = t >> 6, ln = t & 63;
    if (ln == 0) rw[wv] = acc;
    __syncthreads();
    if (t == 0) atomicAdd(&out[130], fabsf(rw[0] + rw[1] + rw[2] + rw[3]) * (1.f / 128.f));
}

extern "C" void kernel_launch(void* const* d_in, const int* in_sizes, int n_in,
                              void* d_out, int out_size, void* d_ws, size_t ws_size,
                              hipStream_t stream) {
    const float* c_hs      = (const float*)d_in[0];
    const float* attention = (const float*)d_in[1];
    const float* coords    = (const float*)d_in[2];
    const float* upd       = (const float*)d_in[3];
    const float* c_valid   = (const float*)d_in[4];
    const float* nm        = (const float*)d_in[5];
    const float* mapping   = (const float*)d_in[6];
    const float* samelb    = (const float*)d_in[7];
    const int*   ei        = (const int*)d_in[8];
    const float* W0 = (const float*)d_in[9],  *b0 = (const float*)d_in[10];
    const float* W1 = (const float*)d_in[11], *b1 = (const float*)d_in[12];
    const float* W2 = (const float*)d_in[13], *b2 = (const float*)d_in[14];
    const float* W3 = (const float*)d_in[15], *b3 = (const float*)d_in[16];
    float* out = (float*)d_out;
    float* ws  = (float*)d_ws;

    hipLaunchKernelGGL(k_init,    dim3(33),       dim3(256), 0, stream, ws, out);
    hipLaunchKernelGGL(k_pool,    dim3(B_, 4),    dim3(256), 0, stream, c_hs, c_valid, ws);
    hipLaunchKernelGGL(k_mlp2,    dim3(B_),       dim3(DFC), 0, stream, ws,
                       W0, b0, W1, b1, W2, b2, W3, b3, out);
    hipLaunchKernelGGL(k_norms,   dim3(B_),       dim3(512), 0, stream, attention, ws);
    hipLaunchKernelGGL(k_maskA,   dim3(8, B_),    dim3(256), 0, stream, attention, mapping, samelb, ws);
    hipLaunchKernelGGL(k_maskB,   dim3(24, B_),   dim3(256), 0, stream, attention, mapping, samelb, ws);
    hipLaunchKernelGGL(k_attnfin, dim3(1),        dim3(128), 0, stream, ws, out);
    hipLaunchKernelGGL(k_kabsch,  dim3(B_),       dim3(N1_), 0, stream, attention, coords, upd, nm, out);
    hipLaunchKernelGGL(k_pair,    dim3(B_),       dim3(256), 0, stream, coords, upd, ei, out);
}

// Round 3
// 403.290 us; speedup vs baseline: 1.4336x; 1.1319x over previous
//
#include <hip/hip_runtime.h>
#include <math.h>

#define B_   128
#define N1_  128
#define N2_  384
#define N_   512
#define E_   1024
#define DIN  64
#define DFC  128

// workspace layout (floats)
#define ACC_TOP  0
#define ACC_BOT  128
#define POOL_OFF 256                          // B*64 = 8192
#define RN_OFF   (POOL_OFF + B_*DIN)          // 8448:  B*N1 rownorms
#define CN_OFF   (RN_OFF + B_*N1_)            // 24832: B*N2 colnorms
#define BI_OFF   (CN_OFF + B_*N2_)            // 73984: B*N1 argmax ints
#define ZERO_CNT (POOL_OFF + B_*DIN)          // zero acc + pool

// ---------------- init ----------------
// grid 33, block 256
__global__ void k_init(float* ws, float* out) {
    int idx = blockIdx.x * 256 + threadIdx.x;
    if (idx < ZERO_CNT) ws[idx] = 0.f;
    if (blockIdx.x == 0 && threadIdx.x < 4) out[128 + threadIdx.x] = 0.f;
}

// ---------------- masked mean-pool ----------------
// grid (B, 8), block 256. Each block: 64 rows.
__global__ void k_pool(const float* __restrict__ c_hs, const float* __restrict__ c_valid,
                       float* __restrict__ ws) {
    __shared__ float4 sred[256];
    int b = blockIdx.x, t = threadIdx.x;
    int chunk = blockIdx.y * 64;
    int d4 = t & 15, rl = t >> 4;
    const float4* X4 = (const float4*)(c_hs + (size_t)b * N_ * DIN);
    const float* V = c_valid + (size_t)b * N_;
    float4 acc = {0.f, 0.f, 0.f, 0.f};
    #pragma unroll
    for (int r = chunk + rl; r < chunk + 64; r += 16) {
        float4 x = X4[r * 16 + d4];
        float v = V[r];
        acc.x += x.x * v; acc.y += x.y * v; acc.z += x.z * v; acc.w += x.w * v;
    }
    sred[t] = acc; __syncthreads();
    for (int off = 128; off >= 16; off >>= 1) {
        if (t < off) {
            float4 o = sred[t + off];
            sred[t].x += o.x; sred[t].y += o.y; sred[t].z += o.z; sred[t].w += o.w;
        }
        __syncthreads();
    }
    if (t < 16) {
        float4 s = sred[t];
        float* p = ws + POOL_OFF + b * DIN + t * 4;
        atomicAdd(&p[0], s.x); atomicAdd(&p[1], s.y);
        atomicAdd(&p[2], s.z); atomicAdd(&p[3], s.w);
    }
}

// ---------------- scores MLP ----------------
// grid B, block 128
__global__ void k_mlp2(const float* __restrict__ ws,
                       const float* __restrict__ W0, const float* __restrict__ b0,
                       const float* __restrict__ W1, const float* __restrict__ b1,
                       const float* __restrict__ W2, const float* __restrict__ b2,
                       const float* __restrict__ W3, const float* __restrict__ b3,
                       float* __restrict__ out) {
    __shared__ float pool[DIN];
    __shared__ float h[DFC];
    __shared__ float h2[DFC];
    __shared__ float part[DFC];
    int b = blockIdx.x, t = threadIdx.x;
    if (t < DIN) pool[t] = ws[POOL_OFF + b * DIN + t] * (1.0f / 128.0f);
    __syncthreads();
    float a = b0[t];
    for (int i = 0; i < DIN; ++i) a += pool[i] * W0[i * DFC + t];
    h[t] = fmaxf(a, 0.f); __syncthreads();
    a = b1[t];
    for (int i = 0; i < DFC; ++i) a += h[i] * W1[i * DFC + t];
    h2[t] = fmaxf(a, 0.f); __syncthreads();
    a = b2[t];
    for (int i = 0; i < DFC; ++i) a += h2[i] * W2[i * DFC + t];
    part[t] = fmaxf(a, 0.f) * W3[t];
    __syncthreads();
    for (int off = 64; off > 0; off >>= 1) { if (t < off) part[t] += part[t + off]; __syncthreads(); }
    if (t == 0) out[b] = 1.f / (1.f + expf(-(part[0] + b3[0])));
}

// ---------------- per-row: rownorm + argmax (one wave per row) ----------------
// grid (B, 32), block 256
__global__ void k_rows(const float* __restrict__ att, float* __restrict__ ws) {
    int b = blockIdx.x, t = threadIdx.x, wv = t >> 6, ln = t & 63;
    int r = blockIdx.y * 4 + wv;
    const float* row = att + ((size_t)b * N1_ + r) * N2_;
    float ssq = 0.f, best = -1e30f; int bidx = 0;
    #pragma unroll
    for (int q = 0; q < 6; ++q) {
        float v = row[ln + 64 * q];
        ssq += v * v;
        if (v > best) { best = v; bidx = ln + 64 * q; }   // ascending: > keeps first
    }
    for (int off = 32; off > 0; off >>= 1) {
        ssq += __shfl_xor(ssq, off, 64);
        float ov = __shfl_xor(best, off, 64);
        int oi = __shfl_xor(bidx, off, 64);
        if (ov > best || (ov == best && oi < bidx)) { best = ov; bidx = oi; }
    }
    if (ln == 0) {
        ws[RN_OFF + b * N1_ + r] = sqrtf(ssq);
        ((int*)ws)[BI_OFF + b * N1_ + r] = bidx;
    }
}

// ---------------- column norms ----------------
// grid (B, 3), block 256
__global__ void k_cols(const float* __restrict__ att, float* __restrict__ ws) {
    __shared__ float sred[256];
    int b = blockIdx.x, t = threadIdx.x;
    int c = blockIdx.y * 128 + (t & 127);
    int half = t >> 7;
    const float* A = att + (size_t)b * N1_ * N2_;
    float s = 0.f;
    #pragma unroll 16
    for (int j = half * 64; j < half * 64 + 64; ++j) { float v = A[j * N2_ + c]; s += v * v; }
    sred[t] = s; __syncthreads();
    if (t < 128) ws[CN_OFF + b * N2_ + blockIdx.y * 128 + t] = sqrtf(sred[t] + sred[t + 128]);
}

__device__ inline float cnt4(float4 m) {
    return (m.x == 1.f ? 1.f : 0.f) + (m.y == 1.f ? 1.f : 0.f)
         + (m.z == 1.f ? 1.f : 0.f) + (m.w == 1.f ? 1.f : 0.f);
}

// ---------------- mask scan: rows [0,128), 16 rows/block ----------------
// grid (8, B), block 256
#define ASTR 388
__global__ void k_maskA(const float* __restrict__ att, const float* __restrict__ mapping,
                        const float* __restrict__ samelb, float* __restrict__ ws) {
    __shared__ float cninv[N2_];
    __shared__ float esh[16 * ASTR];
    __shared__ float rt[4], rb[4];
    int b = blockIdx.y, t = threadIdx.x;
    int i0 = blockIdx.x * 16;
    for (int j = t; j < N2_; j += 256)
        cninv[j] = 1.f / fmaxf(ws[CN_OFF + b * N2_ + j], 1e-12f);
    __syncthreads();
    // stage exp(-att/cn) for 16 rows
    const float4* att4 = (const float4*)(att + ((size_t)(b * N1_ + i0)) * N2_);
    #pragma unroll
    for (int k = 0; k < 6; ++k) {
        int f = t + k * 256;                  // 0..1535
        int r = f / 96, c4 = f - r * 96;
        float4 a = att4[r * 96 + c4];
        int cb = c4 * 4;
        esh[r * ASTR + cb]     = __expf(-a.x * cninv[cb]);
        esh[r * ASTR + cb + 1] = __expf(-a.y * cninv[cb + 1]);
        esh[r * ASTR + cb + 2] = __expf(-a.z * cninv[cb + 2]);
        esh[r * ASTR + cb + 3] = __expf(-a.w * cninv[cb + 3]);
    }
    __syncthreads();
    const float4* m4 = (const float4*)(mapping + ((size_t)b * N_ + i0) * N_);
    const float4* s4 = (const float4*)(samelb + ((size_t)b * N_ + i0) * N_);
    float top = 0.f, bot = 0.f;
    // Phase D: cols 0..127 (atten==0 -> e=1), no divergence
    #pragma unroll
    for (int k = 0; k < 2; ++k) {
        int g = t + k * 256; int r = g >> 5, c4 = g & 31;
        top += cnt4(m4[r * 128 + c4]);
        bot += cnt4(s4[r * 128 + c4]);
    }
    // Phase E: cols 128..511, e = exp(-att/cn) from LDS
    #pragma unroll
    for (int k = 0; k < 6; ++k) {
        int g = t + k * 256; int r = g / 96, c4 = g - r * 96;
        float4 mv = m4[r * 128 + 32 + c4];
        float4 sv = s4[r * 128 + 32 + c4];
        int eb = r * ASTR + c4 * 4;
        float e0 = esh[eb], e1 = esh[eb + 1], e2 = esh[eb + 2], e3 = esh[eb + 3];
        top += (mv.x == 1.f ? e0 : 0.f) + (mv.y == 1.f ? e1 : 0.f)
             + (mv.z == 1.f ? e2 : 0.f) + (mv.w == 1.f ? e3 : 0.f);
        bot += (sv.x == 1.f ? e0 : 0.f) + (sv.y == 1.f ? e1 : 0.f)
             + (sv.z == 1.f ? e2 : 0.f) + (sv.w == 1.f ? e3 : 0.f);
    }
    for (int off = 32; off > 0; off >>= 1) {
        top += __shfl_down(top, off, 64);
        bot += __shfl_down(bot, off, 64);
    }
    int wv = t >> 6, ln = t & 63;
    if (ln == 0) { rt[wv] = top; rb[wv] = bot; }
    __syncthreads();
    if (t == 0) {
        atomicAdd(&ws[ACC_TOP + b], rt[0] + rt[1] + rt[2] + rt[3]);
        atomicAdd(&ws[ACC_BOT + b], rb[0] + rb[1] + rb[2] + rb[3]);
    }
}

// ---------------- mask scan: rows [128,512), 16 rows/block ----------------
// grid (24, B), block 256
#define BSTR 132
__global__ void k_maskB(const float* __restrict__ att, const float* __restrict__ mapping,
                        const float* __restrict__ samelb, float* __restrict__ ws) {
    __shared__ float rinv[N1_];
    __shared__ float tile[16 * BSTR];
    __shared__ float rt[4], rb[4];
    int b = blockIdx.y, t = threadIdx.x;
    int k0 = blockIdx.x * 16;
    if (t < N1_) rinv[t] = 1.f / fmaxf(ws[RN_OFF + b * N1_ + t], 1e-12f);
    __syncthreads();
    // transpose-load + exp: tile[r][j] = exp(-att[j, k0+r] / rn[j])
    int r4 = t & 3;
    for (int j = (t >> 2); j < N1_; j += 64) {
        float4 a = *(const float4*)&att[((size_t)(b * N1_ + j)) * N2_ + k0 + r4 * 4];
        float rv = rinv[j];
        tile[(r4 * 4 + 0) * BSTR + j] = __expf(-a.x * rv);
        tile[(r4 * 4 + 1) * BSTR + j] = __expf(-a.y * rv);
        tile[(r4 * 4 + 2) * BSTR + j] = __expf(-a.z * rv);
        tile[(r4 * 4 + 3) * BSTR + j] = __expf(-a.w * rv);
    }
    __syncthreads();
    const float4* m4 = (const float4*)(mapping + ((size_t)b * N_ + N1_ + k0) * N_);
    const float4* s4 = (const float4*)(samelb + ((size_t)b * N_ + N1_ + k0) * N_);
    float top = 0.f, bot = 0.f;
    // Phase D: cols 0..127, e from tile
    #pragma unroll
    for (int k = 0; k < 2; ++k) {
        int g = t + k * 256; int r = g >> 5, c4 = g & 31;
        float4 mv = m4[r * 128 + c4];
        float4 sv = s4[r * 128 + c4];
        int eb = r * BSTR + c4 * 4;
        float e0 = tile[eb], e1 = tile[eb + 1], e2 = tile[eb + 2], e3 = tile[eb + 3];
        top += (mv.x == 1.f ? e0 : 0.f) + (mv.y == 1.f ? e1 : 0.f)
             + (mv.z == 1.f ? e2 : 0.f) + (mv.w == 1.f ? e3 : 0.f);
        bot += (sv.x == 1.f ? e0 : 0.f) + (sv.y == 1.f ? e1 : 0.f)
             + (sv.z == 1.f ? e2 : 0.f) + (sv.w == 1.f ? e3 : 0.f);
    }
    // Phase E: cols 128..511 (atten==0 -> e=1)
    #pragma unroll
    for (int k = 0; k < 6; ++k) {
        int g = t + k * 256; int r = g / 96, c4 = g - r * 96;
        top += cnt4(m4[r * 128 + 32 + c4]);
        bot += cnt4(s4[r * 128 + 32 + c4]);
    }
    for (int off = 32; off > 0; off >>= 1) {
        top += __shfl_down(top, off, 64);
        bot += __shfl_down(bot, off, 64);
    }
    int wv = t >> 6, ln = t & 63;
    if (ln == 0) { rt[wv] = top; rb[wv] = bot; }
    __syncthreads();
    if (t == 0) {
        atomicAdd(&ws[ACC_TOP + b], rt[0] + rt[1] + rt[2] + rt[3]);
        atomicAdd(&ws[ACC_BOT + b], rb[0] + rb[1] + rb[2] + rb[3]);
    }
}

// ---------------- Kabsch + pairdst + attn finalize ----------------
__device__ inline float bred(float* s, float v, int t) {
    __syncthreads();
    s[t] = v; __syncthreads();
    for (int off = 64; off > 0; off >>= 1) { if (t < off) s[t] += s[t + off]; __syncthreads(); }
    float r = s[0]; __syncthreads(); return r;
}

// grid B, block 128
__global__ void k_kabsch(const float* __restrict__ coords, const float* __restrict__ upd,
                         const float* __restrict__ nm, const int* __restrict__ ei,
                         const float* __restrict__ ws, float* __restrict__ out) {
    __shared__ float sred[128];
    __shared__ float Rsh[9], Tsh[3];
    int b = blockIdx.x, t = threadIdx.x;
    int bidx = ((const int*)ws)[BI_OFF + b * N1_ + t];
    float P[3], Q[3];
    const float* up = upd + ((size_t)b * N_ + t) * 3;
    P[0] = up[0]; P[1] = up[1]; P[2] = up[2];
    const float* qp = coords + ((size_t)b * N_ + N1_ + bidx) * 3;
    Q[0] = qp[0]; Q[1] = qp[1]; Q[2] = qp[2];
    float Pm[3], Qm[3];
    for (int a = 0; a < 3; ++a) Pm[a] = bred(sred, P[a], t) * (1.f / 128.f);
    for (int a = 0; a < 3; ++a) Qm[a] = bred(sred, Q[a], t) * (1.f / 128.f);
    float H[9];
    for (int a = 0; a < 3; ++a)
        for (int c = 0; c < 3; ++c)
            H[a * 3 + c] = bred(sred, (P[a] - Pm[a]) * (Q[c] - Qm[c]), t) * (1.f / 8.f);
    if (t == 0) {
        double Hd[3][3];
        for (int a = 0; a < 3; ++a) for (int c = 0; c < 3; ++c) Hd[a][c] = (double)H[a * 3 + c];
        double A[3][3], V[3][3] = {{1,0,0},{0,1,0},{0,0,1}};
        for (int i = 0; i < 3; ++i)
            for (int j = 0; j < 3; ++j) {
                double s2 = 0; for (int c = 0; c < 3; ++c) s2 += Hd[c][i] * Hd[c][j];
                A[i][j] = s2;
            }
        for (int sweep = 0; sweep < 12; ++sweep) {
            const int PQ[3][2] = {{0,1},{0,2},{1,2}};
            for (int r = 0; r < 3; ++r) {
                int p = PQ[r][0], q = PQ[r][1];
                double apq = A[p][q];
                if (fabs(apq) < 1e-300) continue;
                double tau = (A[q][q] - A[p][p]) / (2.0 * apq);
                double tt = (tau >= 0 ? 1.0 : -1.0) / (fabs(tau) + sqrt(1.0 + tau * tau));
                double c = 1.0 / sqrt(1.0 + tt * tt), s = tt * c;
                for (int k = 0; k < 3; ++k) { double akp = A[k][p], akq = A[k][q]; A[k][p] = c * akp - s * akq; A[k][q] = s * akp + c * akq; }
                for (int k = 0; k < 3; ++k) { double apk = A[p][k], aqk = A[q][k]; A[p][k] = c * apk - s * aqk; A[q][k] = s * apk + c * aqk; }
                for (int k = 0; k < 3; ++k) { double vkp = V[k][p], vkq = V[k][q]; V[k][p] = c * vkp - s * vkq; V[k][q] = s * vkp + c * vkq; }
            }
        }
        double lam[3] = {A[0][0], A[1][1], A[2][2]};
        int id[3] = {0, 1, 2};
        if (lam[id[0]] < lam[id[1]]) { int x = id[0]; id[0] = id[1]; id[1] = x; }
        if (lam[id[0]] < lam[id[2]]) { int x = id[0]; id[0] = id[2]; id[2] = x; }
        if (lam[id[1]] < lam[id[2]]) { int x = id[1]; id[1] = id[2]; id[2] = x; }
        double u[3][3], v[3][3], sv[3];
        for (int i = 0; i < 3; ++i) {
            for (int k = 0; k < 3; ++k) v[i][k] = V[k][id[i]];
            double uv[3];
            for (int c = 0; c < 3; ++c) uv[c] = Hd[c][0] * v[i][0] + Hd[c][1] * v[i][1] + Hd[c][2] * v[i][2];
            double n = sqrt(uv[0] * uv[0] + uv[1] * uv[1] + uv[2] * uv[2]);
            sv[i] = n;
            if (n > 1e-150) { u[i][0] = uv[0] / n; u[i][1] = uv[1] / n; u[i][2] = uv[2] / n; }
            else { u[i][0] = u[i][1] = u[i][2] = 0.0; }
        }
        if (sv[2] < 1e-12 * fmax(sv[0], 1e-300)) {
            u[2][0] = u[0][1] * u[1][2] - u[0][2] * u[1][1];
            u[2][1] = u[0][2] * u[1][0] - u[0][0] * u[1][2];
            u[2][2] = u[0][0] * u[1][1] - u[0][1] * u[1][0];
        }
        double det = Hd[0][0] * (Hd[1][1] * Hd[2][2] - Hd[1][2] * Hd[2][1])
                   - Hd[0][1] * (Hd[1][0] * Hd[2][2] - Hd[1][2] * Hd[2][0])
                   + Hd[0][2] * (Hd[1][0] * Hd[2][1] - Hd[1][1] * Hd[2][0]);
        double dsg = (det > 0.0) ? 1.0 : ((det < 0.0) ? -1.0 : 0.0);
        for (int a = 0; a < 3; ++a)
            for (int c = 0; c < 3; ++c)
                Rsh[a * 3 + c] = (float)(u[0][a] * v[0][c] + u[1][a] * v[1][c] + dsg * u[2][a] * v[2][c]);
        for (int a = 0; a < 3; ++a)
            Tsh[a] = Qm[a] - (Rsh[a * 3] * Pm[0] + Rsh[a * 3 + 1] * Pm[1] + Rsh[a * 3 + 2] * Pm[2]);
    }
    __syncthreads();
    float Pp[3];
    for (int a = 0; a < 3; ++a)
        Pp[a] = Rsh[a * 3] * P[0] + Rsh[a * 3 + 1] * P[1] + Rsh[a * 3 + 2] * P[2] + Tsh[a];
    float mk = (nm[b * N1_ + t] > 0.5f) ? 1.f : 0.f;
    float dx = Pp[0] - Q[0], dy = Pp[1] - Q[1], dz = Pp[2] - Q[2];
    float rsum = bred(sred, mk * (dx * dx + dy * dy + dz * dz), t);
    float msum = bred(sred, mk, t);
    float Ppm[3];
    for (int a = 0; a < 3; ++a) Ppm[a] = bred(sred, Pp[a], t) * (1.f / 128.f);
    if (t == 0) {
        float cnt = fmaxf(msum * 3.f, 1.f);
        atomicAdd(&out[129], (rsum / cnt) * (1.f / 128.f));
        float cen = 0.f;
        for (int a = 0; a < 3; ++a) { float d2 = Ppm[a] - Qm[a]; cen += d2 * d2; }
        atomicAdd(&out[131], (cen / 3.f) * (1.f / 128.f));
    }
    // ---- fused pairdst for this batch ----
    const float* C = coords + (size_t)b * N_ * 3;
    const float* U = upd + (size_t)b * N_ * 3;
    const int* e = ei + (size_t)b * E_ * 2;
    float acc = 0.f;
    for (int idx = t; idx < E_; idx += 128) {
        int a0 = e[idx * 2], a1 = e[idx * 2 + 1];
        float ex = C[a0 * 3] - C[a1 * 3], ey = C[a0 * 3 + 1] - C[a1 * 3 + 1], ez = C[a0 * 3 + 2] - C[a1 * 3 + 2];
        float d0 = sqrtf(ex * ex + ey * ey + ez * ez + 1e-12f);
        ex = U[a0 * 3] - U[a1 * 3]; ey = U[a0 * 3 + 1] - U[a1 * 3 + 1]; ez = U[a0 * 3 + 2] - U[a1 * 3 + 2];
        float d1 = sqrtf(ex * ex + ey * ey + ez * ez + 1e-12f);
        acc += d1 - d0;
    }
    float psum = bred(sred, acc, t);
    if (t == 0) atomicAdd(&out[130], fabsf(psum) * (1.f / 128.f));
    // ---- fused attn_loss finalize (masks completed before this kernel) ----
    if (b == 0) {
        float top = ws[ACC_TOP + t], bot = ws[ACC_BOT + t];
        float v = top / (bot - top + 1.0f);
        float s = bred(sred, v, t);
        if (t == 0) out[128] = s * (1.0f / 128.0f);
    }
}

extern "C" void kernel_launch(void* const* d_in, const int* in_sizes, int n_in,
                              void* d_out, int out_size, void* d_ws, size_t ws_size,
                              hipStream_t stream) {
    const float* c_hs      = (const float*)d_in[0];
    const float* attention = (const float*)d_in[1];
    const float* coords    = (const float*)d_in[2];
    const float* upd       = (const float*)d_in[3];
    const float* c_valid   = (const float*)d_in[4];
    const float* nm        = (const float*)d_in[5];
    const float* mapping   = (const float*)d_in[6];
    const float* samelb    = (const float*)d_in[7];
    const int*   ei        = (const int*)d_in[8];
    const float* W0 = (const float*)d_in[9],  *b0 = (const float*)d_in[10];
    const float* W1 = (const float*)d_in[11], *b1 = (const float*)d_in[12];
    const float* W2 = (const float*)d_in[13], *b2 = (const float*)d_in[14];
    const float* W3 = (const float*)d_in[15], *b3 = (const float*)d_in[16];
    float* out = (float*)d_out;
    float* ws  = (float*)d_ws;

    hipLaunchKernelGGL(k_init,   dim3(33),      dim3(256), 0, stream, ws, out);
    hipLaunchKernelGGL(k_pool,   dim3(B_, 8),   dim3(256), 0, stream, c_hs, c_valid, ws);
    hipLaunchKernelGGL(k_mlp2,   dim3(B_),      dim3(DFC), 0, stream, ws,
                       W0, b0, W1, b1, W2, b2, W3, b3, out);
    hipLaunchKernelGGL(k_rows,   dim3(B_, 32),  dim3(256), 0, stream, attention, ws);
    hipLaunchKernelGGL(k_cols,   dim3(B_, 3),   dim3(256), 0, stream, attention, ws);
    hipLaunchKernelGGL(k_maskA,  dim3(8, B_),   dim3(256), 0, stream, attention, mapping, samelb, ws);
    hipLaunchKernelGGL(k_maskB,  dim3(24, B_),  dim3(256), 0, stream, attention, mapping, samelb, ws);
    hipLaunchKernelGGL(k_kabsch, dim3(B_),      dim3(N1_), 0, stream, coords, upd, nm, ei, ws, out);
}

// Round 4
// 389.907 us; speedup vs baseline: 1.4828x; 1.0343x over previous
//
#include <hip/hip_runtime.h>
#include <math.h>

#define B_   128
#define N1_  128
#define N2_  384
#define N_   512
#define E_   1024
#define DIN  64
#define DFC  128

// workspace layout (floats)
#define ACC_TOP  0
#define ACC_BOT  128
#define POOL_OFF 256                          // B*64 = 8192
#define RNI_OFF  (POOL_OFF + B_*DIN)          // 8448:  B*N1 reciprocal rownorms
#define CNI_OFF  (RNI_OFF + B_*N1_)           // 24832: B*N2 reciprocal colnorms
#define BI_OFF   (CNI_OFF + B_*N2_)           // 73984: B*N1 argmax ints
#define EB_OFF   (BI_OFF + B_*N1_)            // 90368: B*384*128 exp-matrix (25 MB)
#define ZERO_CNT (POOL_OFF + B_*DIN)

// ---------------- init ----------------
// grid 33, block 256
__global__ void k_init(float* ws, float* out) {
    int idx = blockIdx.x * 256 + threadIdx.x;
    if (idx < ZERO_CNT) ws[idx] = 0.f;
    if (blockIdx.x == 0 && threadIdx.x < 4) out[128 + threadIdx.x] = 0.f;
}

// ---------------- masked mean-pool ----------------
// grid (B, 8), block 256
__global__ void k_pool(const float* __restrict__ c_hs, const float* __restrict__ c_valid,
                       float* __restrict__ ws) {
    __shared__ float4 sred[256];
    int b = blockIdx.x, t = threadIdx.x;
    int chunk = blockIdx.y * 64;
    int d4 = t & 15, rl = t >> 4;
    const float4* X4 = (const float4*)(c_hs + (size_t)b * N_ * DIN);
    const float* V = c_valid + (size_t)b * N_;
    float4 acc = {0.f, 0.f, 0.f, 0.f};
    #pragma unroll
    for (int r = chunk + rl; r < chunk + 64; r += 16) {
        float4 x = X4[r * 16 + d4];
        float v = V[r];
        acc.x += x.x * v; acc.y += x.y * v; acc.z += x.z * v; acc.w += x.w * v;
    }
    sred[t] = acc; __syncthreads();
    for (int off = 128; off >= 16; off >>= 1) {
        if (t < off) {
            float4 o = sred[t + off];
            sred[t].x += o.x; sred[t].y += o.y; sred[t].z += o.z; sred[t].w += o.w;
        }
        __syncthreads();
    }
    if (t < 16) {
        float4 s = sred[t];
        float* p = ws + POOL_OFF + b * DIN + t * 4;
        atomicAdd(&p[0], s.x); atomicAdd(&p[1], s.y);
        atomicAdd(&p[2], s.z); atomicAdd(&p[3], s.w);
    }
}

// ---------------- scores MLP ----------------
// grid B, block 128
__global__ void k_mlp2(const float* __restrict__ ws,
                       const float* __restrict__ W0, const float* __restrict__ b0,
                       const float* __restrict__ W1, const float* __restrict__ b1,
                       const float* __restrict__ W2, const float* __restrict__ b2,
                       const float* __restrict__ W3, const float* __restrict__ b3,
                       float* __restrict__ out) {
    __shared__ float pool[DIN];
    __shared__ float h[DFC];
    __shared__ float h2[DFC];
    __shared__ float part[DFC];
    int b = blockIdx.x, t = threadIdx.x;
    if (t < DIN) pool[t] = ws[POOL_OFF + b * DIN + t] * (1.0f / 128.0f);
    __syncthreads();
    float a = b0[t];
    #pragma unroll
    for (int i = 0; i < DIN; ++i) a += pool[i] * W0[i * DFC + t];
    h[t] = fmaxf(a, 0.f); __syncthreads();
    a = b1[t];
    #pragma unroll
    for (int i = 0; i < DFC; ++i) a += h[i] * W1[i * DFC + t];
    h2[t] = fmaxf(a, 0.f); __syncthreads();
    a = b2[t];
    #pragma unroll
    for (int i = 0; i < DFC; ++i) a += h2[i] * W2[i * DFC + t];
    part[t] = fmaxf(a, 0.f) * W3[t];
    __syncthreads();
    for (int off = 64; off > 0; off >>= 1) { if (t < off) part[t] += part[t + off]; __syncthreads(); }
    if (t == 0) out[b] = 1.f / (1.f + expf(-(part[0] + b3[0])));
}

// ---------------- per-row: reciprocal rownorm + argmax (one wave per row) ----------------
// grid (B, 32), block 256
__global__ void k_rows(const float* __restrict__ att, float* __restrict__ ws) {
    int b = blockIdx.x, t = threadIdx.x, wv = t >> 6, ln = t & 63;
    int r = blockIdx.y * 4 + wv;
    const float* row = att + ((size_t)b * N1_ + r) * N2_;
    float ssq = 0.f, best = -1e30f; int bidx = 0;
    #pragma unroll
    for (int q = 0; q < 6; ++q) {
        float v = row[ln + 64 * q];
        ssq += v * v;
        if (v > best) { best = v; bidx = ln + 64 * q; }   // ascending: > keeps first
    }
    for (int off = 32; off > 0; off >>= 1) {
        ssq += __shfl_xor(ssq, off, 64);
        float ov = __shfl_xor(best, off, 64);
        int oi = __shfl_xor(bidx, off, 64);
        if (ov > best || (ov == best && oi < bidx)) { best = ov; bidx = oi; }
    }
    if (ln == 0) {
        ws[RNI_OFF + b * N1_ + r] = 1.f / fmaxf(sqrtf(ssq), 1e-12f);
        ((int*)ws)[BI_OFF + b * N1_ + r] = bidx;
    }
}

// ---------------- reciprocal column norms ----------------
// grid (B, 6), block 256: 64 cols/block, 4 row-quarters
__global__ void k_cols(const float* __restrict__ att, float* __restrict__ ws) {
    __shared__ float sred[256];
    int b = blockIdx.x, t = threadIdx.x;
    int c = blockIdx.y * 64 + (t & 63);
    int q = t >> 6;
    const float* A = att + (size_t)b * N1_ * N2_;
    float s = 0.f;
    #pragma unroll 8
    for (int j = q * 32; j < q * 32 + 32; ++j) { float v = A[j * N2_ + c]; s += v * v; }
    sred[t] = s; __syncthreads();
    if (t < 64)
        ws[CNI_OFF + b * N2_ + blockIdx.y * 64 + t] =
            1.f / fmaxf(sqrtf(sred[t] + sred[t + 64] + sred[t + 128] + sred[t + 192]), 1e-12f);
}

// ---------------- prep: eB[r][j] = exp(-att[j,r]*rinv[j]) (transposed) ----------------
// grid (12, B), block 256. Strip of 32 att-cols.
#define TP 129
__global__ void k_prep(const float* __restrict__ att, float* __restrict__ ws) {
    __shared__ float tile[32 * TP];
    __shared__ float rinv[N1_];
    int b = blockIdx.y, t = threadIdx.x;
    int r0 = blockIdx.x * 32;
    if (t < N1_) rinv[t] = ws[RNI_OFF + b * N1_ + t];
    __syncthreads();
    const float4* att4 = (const float4*)(att + (size_t)b * N1_ * N2_);
    int c8 = t & 7, jb = t >> 3;                 // 32 rows per pass
    #pragma unroll
    for (int p = 0; p < 4; ++p) {
        int j = jb + p * 32;
        float4 a = att4[j * 96 + blockIdx.x * 8 + c8];
        float rv = rinv[j];
        tile[(c8 * 4 + 0) * TP + j] = a.x * rv;
        tile[(c8 * 4 + 1) * TP + j] = a.y * rv;
        tile[(c8 * 4 + 2) * TP + j] = a.z * rv;
        tile[(c8 * 4 + 3) * TP + j] = a.w * rv;
    }
    __syncthreads();
    int j4 = t & 31, cb = t >> 5;                // 8 eB-rows per pass
    float4* eb4 = (float4*)(ws + EB_OFF + ((size_t)b * N2_ + r0) * N1_);
    #pragma unroll
    for (int p = 0; p < 4; ++p) {
        int c = cb + p * 8;
        float4 e;
        e.x = __expf(-tile[c * TP + j4 * 4]);
        e.y = __expf(-tile[c * TP + j4 * 4 + 1]);
        e.z = __expf(-tile[c * TP + j4 * 4 + 2]);
        e.w = __expf(-tile[c * TP + j4 * 4 + 3]);
        eb4[c * 32 + j4] = e;
    }
}

__device__ inline float cnt4(float4 m) {
    return (m.x == 1.f ? 1.f : 0.f) + (m.y == 1.f ? 1.f : 0.f)
         + (m.z == 1.f ? 1.f : 0.f) + (m.w == 1.f ? 1.f : 0.f);
}

// ---------------- fused mask scan: all 512 rows, 16 rows/block ----------------
// grid (32, B), block 256
__global__ void k_scan(const float* __restrict__ att, const float* __restrict__ mapping,
                       const float* __restrict__ samelb, float* __restrict__ ws) {
    __shared__ float cninv[N2_];
    __shared__ float rt[4], rb[4];
    int b = blockIdx.y, t = threadIdx.x;
    int i0 = blockIdx.x * 16;
    const float4* m4 = (const float4*)(mapping + ((size_t)b * N_ + i0) * N_);
    const float4* s4 = (const float4*)(samelb + ((size_t)b * N_ + i0) * N_);
    float top = 0.f, bot = 0.f;
    if (i0 < N1_) {
        // type A: rows [0,128). cols<128: count; cols>=128: exp(-att*cninv) inline
        for (int j = t; j < N2_; j += 256) cninv[j] = ws[CNI_OFF + b * N2_ + j];
        __syncthreads();
        #pragma unroll
        for (int k = 0; k < 2; ++k) {            // diag 16 rows x 32 float4
            int g = t + k * 256; int r = g >> 5, c4 = g & 31;
            top += cnt4(m4[r * 128 + c4]);
            bot += cnt4(s4[r * 128 + c4]);
        }
        const float4* a4 = (const float4*)(att + ((size_t)b * N1_ + i0) * N2_);
        #pragma unroll
        for (int k = 0; k < 6; ++k) {            // 16 rows x 96 float4
            int g = t + k * 256; int r = g / 96, c4 = g - r * 96;
            float4 mv = m4[r * 128 + 32 + c4];
            float4 sv = s4[r * 128 + 32 + c4];
            float4 a  = a4[r * 96 + c4];
            int cb = c4 * 4;
            float e0 = __expf(-a.x * cninv[cb]);
            float e1 = __expf(-a.y * cninv[cb + 1]);
            float e2 = __expf(-a.z * cninv[cb + 2]);
            float e3 = __expf(-a.w * cninv[cb + 3]);
            top += (mv.x == 1.f ? e0 : 0.f) + (mv.y == 1.f ? e1 : 0.f)
                 + (mv.z == 1.f ? e2 : 0.f) + (mv.w == 1.f ? e3 : 0.f);
            bot += (sv.x == 1.f ? e0 : 0.f) + (sv.y == 1.f ? e1 : 0.f)
                 + (sv.z == 1.f ? e2 : 0.f) + (sv.w == 1.f ? e3 : 0.f);
        }
    } else {
        // type B: rows [128,512). cols<128: e from precomputed eB; cols>=128: count
        const float4* eb4 = (const float4*)(ws + EB_OFF + ((size_t)b * N2_ + (i0 - N1_)) * N1_);
        #pragma unroll
        for (int k = 0; k < 2; ++k) {            // 16 rows x 32 float4
            int g = t + k * 256; int r = g >> 5, c4 = g & 31;
            float4 mv = m4[r * 128 + c4];
            float4 sv = s4[r * 128 + c4];
            float4 e  = eb4[r * 32 + c4];
            top += (mv.x == 1.f ? e.x : 0.f) + (mv.y == 1.f ? e.y : 0.f)
                 + (mv.z == 1.f ? e.z : 0.f) + (mv.w == 1.f ? e.w : 0.f);
            bot += (sv.x == 1.f ? e.x : 0.f) + (sv.y == 1.f ? e.y : 0.f)
                 + (sv.z == 1.f ? e.z : 0.f) + (sv.w == 1.f ? e.w : 0.f);
        }
        #pragma unroll
        for (int k = 0; k < 6; ++k) {            // 16 rows x 96 float4
            int g = t + k * 256; int r = g / 96, c4 = g - r * 96;
            top += cnt4(m4[r * 128 + 32 + c4]);
            bot += cnt4(s4[r * 128 + 32 + c4]);
        }
    }
    for (int off = 32; off > 0; off >>= 1) {
        top += __shfl_down(top, off, 64);
        bot += __shfl_down(bot, off, 64);
    }
    int wv = t >> 6, ln = t & 63;
    if (ln == 0) { rt[wv] = top; rb[wv] = bot; }
    __syncthreads();
    if (t == 0) {
        atomicAdd(&ws[ACC_TOP + b], rt[0] + rt[1] + rt[2] + rt[3]);
        atomicAdd(&ws[ACC_BOT + b], rb[0] + rb[1] + rb[2] + rb[3]);
    }
}

// ---------------- Kabsch + pairdst + attn finalize ----------------
// block = 128 (2 waves): shuffle-based block reduction, 2 barriers
__device__ inline float bred(float* s2, float v, int t) {
    for (int off = 32; off > 0; off >>= 1) v += __shfl_down(v, off, 64);
    if ((t & 63) == 0) s2[t >> 6] = v;
    __syncthreads();
    float r = s2[0] + s2[1];
    __syncthreads();
    return r;
}

// grid B, block 128
__global__ void k_kabsch(const float* __restrict__ coords, const float* __restrict__ upd,
                         const float* __restrict__ nm, const int* __restrict__ ei,
                         const float* __restrict__ ws, float* __restrict__ out) {
    __shared__ float s2[2];
    __shared__ float Rsh[9], Tsh[3];
    int b = blockIdx.x, t = threadIdx.x;
    int bidx = ((const int*)ws)[BI_OFF + b * N1_ + t];
    float P[3], Q[3];
    const float* up = upd + ((size_t)b * N_ + t) * 3;
    P[0] = up[0]; P[1] = up[1]; P[2] = up[2];
    const float* qp = coords + ((size_t)b * N_ + N1_ + bidx) * 3;
    Q[0] = qp[0]; Q[1] = qp[1]; Q[2] = qp[2];
    float Pm[3], Qm[3];
    for (int a = 0; a < 3; ++a) Pm[a] = bred(s2, P[a], t) * (1.f / 128.f);
    for (int a = 0; a < 3; ++a) Qm[a] = bred(s2, Q[a], t) * (1.f / 128.f);
    float H[9];
    for (int a = 0; a < 3; ++a)
        for (int c = 0; c < 3; ++c)
            H[a * 3 + c] = bred(s2, (P[a] - Pm[a]) * (Q[c] - Qm[c]), t) * (1.f / 8.f);
    if (t == 0) {
        double Hd[3][3];
        for (int a = 0; a < 3; ++a) for (int c = 0; c < 3; ++c) Hd[a][c] = (double)H[a * 3 + c];
        double A[3][3], V[3][3] = {{1,0,0},{0,1,0},{0,0,1}};
        for (int i = 0; i < 3; ++i)
            for (int j = 0; j < 3; ++j) {
                double z = 0; for (int c = 0; c < 3; ++c) z += Hd[c][i] * Hd[c][j];
                A[i][j] = z;
            }
        for (int sweep = 0; sweep < 8; ++sweep) {
            const int PQ[3][2] = {{0,1},{0,2},{1,2}};
            for (int r = 0; r < 3; ++r) {
                int p = PQ[r][0], q = PQ[r][1];
                double apq = A[p][q];
                if (fabs(apq) < 1e-300) continue;
                double tau = (A[q][q] - A[p][p]) / (2.0 * apq);
                double tt = (tau >= 0 ? 1.0 : -1.0) / (fabs(tau) + sqrt(1.0 + tau * tau));
                double c = 1.0 / sqrt(1.0 + tt * tt), s = tt * c;
                for (int k = 0; k < 3; ++k) { double akp = A[k][p], akq = A[k][q]; A[k][p] = c * akp - s * akq; A[k][q] = s * akp + c * akq; }
                for (int k = 0; k < 3; ++k) { double apk = A[p][k], aqk = A[q][k]; A[p][k] = c * apk - s * aqk; A[q][k] = s * apk + c * aqk; }
                for (int k = 0; k < 3; ++k) { double vkp = V[k][p], vkq = V[k][q]; V[k][p] = c * vkp - s * vkq; V[k][q] = s * vkp + c * vkq; }
            }
        }
        double lam[3] = {A[0][0], A[1][1], A[2][2]};
        int id[3] = {0, 1, 2};
        if (lam[id[0]] < lam[id[1]]) { int x = id[0]; id[0] = id[1]; id[1] = x; }
        if (lam[id[0]] < lam[id[2]]) { int x = id[0]; id[0] = id[2]; id[2] = x; }
        if (lam[id[1]] < lam[id[2]]) { int x = id[1]; id[1] = id[2]; id[2] = x; }
        double u[3][3], v[3][3], sv[3];
        for (int i = 0; i < 3; ++i) {
            for (int k = 0; k < 3; ++k) v[i][k] = V[k][id[i]];
            double uv[3];
            for (int c = 0; c < 3; ++c) uv[c] = Hd[c][0] * v[i][0] + Hd[c][1] * v[i][1] + Hd[c][2] * v[i][2];
            double n = sqrt(uv[0] * uv[0] + uv[1] * uv[1] + uv[2] * uv[2]);
            sv[i] = n;
            if (n > 1e-150) { u[i][0] = uv[0] / n; u[i][1] = uv[1] / n; u[i][2] = uv[2] / n; }
            else { u[i][0] = u[i][1] = u[i][2] = 0.0; }
        }
        if (sv[2] < 1e-12 * fmax(sv[0], 1e-300)) {
            u[2][0] = u[0][1] * u[1][2] - u[0][2] * u[1][1];
            u[2][1] = u[0][2] * u[1][0] - u[0][0] * u[1][2];
            u[2][2] = u[0][0] * u[1][1] - u[0][1] * u[1][0];
        }
        double det = Hd[0][0] * (Hd[1][1] * Hd[2][2] - Hd[1][2] * Hd[2][1])
                   - Hd[0][1] * (Hd[1][0] * Hd[2][2] - Hd[1][2] * Hd[2][0])
                   + Hd[0][2] * (Hd[1][0] * Hd[2][1] - Hd[1][1] * Hd[2][0]);
        double dsg = (det > 0.0) ? 1.0 : ((det < 0.0) ? -1.0 : 0.0);
        for (int a = 0; a < 3; ++a)
            for (int c = 0; c < 3; ++c)
                Rsh[a * 3 + c] = (float)(u[0][a] * v[0][c] + u[1][a] * v[1][c] + dsg * u[2][a] * v[2][c]);
        for (int a = 0; a < 3; ++a)
            Tsh[a] = Qm[a] - (Rsh[a * 3] * Pm[0] + Rsh[a * 3 + 1] * Pm[1] + Rsh[a * 3 + 2] * Pm[2]);
    }
    __syncthreads();
    float Pp[3];
    for (int a = 0; a < 3; ++a)
        Pp[a] = Rsh[a * 3] * P[0] + Rsh[a * 3 + 1] * P[1] + Rsh[a * 3 + 2] * P[2] + Tsh[a];
    float mk = (nm[b * N1_ + t] > 0.5f) ? 1.f : 0.f;
    float dx = Pp[0] - Q[0], dy = Pp[1] - Q[1], dz = Pp[2] - Q[2];
    float rsum = bred(s2, mk * (dx * dx + dy * dy + dz * dz), t);
    float msum = bred(s2, mk, t);
    float Ppm[3];
    for (int a = 0; a < 3; ++a) Ppm[a] = bred(s2, Pp[a], t) * (1.f / 128.f);
    if (t == 0) {
        float cnt = fmaxf(msum * 3.f, 1.f);
        atomicAdd(&out[129], (rsum / cnt) * (1.f / 128.f));
        float cen = 0.f;
        for (int a = 0; a < 3; ++a) { float d2 = Ppm[a] - Qm[a]; cen += d2 * d2; }
        atomicAdd(&out[131], (cen / 3.f) * (1.f / 128.f));
    }
    // ---- fused pairdst ----
    const float* C = coords + (size_t)b * N_ * 3;
    const float* U = upd + (size_t)b * N_ * 3;
    const int* e = ei + (size_t)b * E_ * 2;
    float acc = 0.f;
    for (int idx = t; idx < E_; idx += 128) {
        int a0 = e[idx * 2], a1 = e[idx * 2 + 1];
        float ex = C[a0 * 3] - C[a1 * 3], ey = C[a0 * 3 + 1] - C[a1 * 3 + 1], ez = C[a0 * 3 + 2] - C[a1 * 3 + 2];
        float d0 = sqrtf(ex * ex + ey * ey + ez * ez + 1e-12f);
        ex = U[a0 * 3] - U[a1 * 3]; ey = U[a0 * 3 + 1] - U[a1 * 3 + 1]; ez = U[a0 * 3 + 2] - U[a1 * 3 + 2];
        float d1 = sqrtf(ex * ex + ey * ey + ez * ez + 1e-12f);
        acc += d1 - d0;
    }
    float psum = bred(s2, acc, t);
    if (t == 0) atomicAdd(&out[130], fabsf(psum) * (1.f / 128.f));
    // ---- fused attn_loss finalize ----
    if (b == 0) {
        float top = ws[ACC_TOP + t], bot = ws[ACC_BOT + t];
        float v = top / (bot - top + 1.0f);
        float s = bred(s2, v, t);
        if (t == 0) out[128] = s * (1.0f / 128.0f);
    }
}

extern "C" void kernel_launch(void* const* d_in, const int* in_sizes, int n_in,
                              void* d_out, int out_size, void* d_ws, size_t ws_size,
                              hipStream_t stream) {
    const float* c_hs      = (const float*)d_in[0];
    const float* attention = (const float*)d_in[1];
    const float* coords    = (const float*)d_in[2];
    const float* upd       = (const float*)d_in[3];
    const float* c_valid   = (const float*)d_in[4];
    const float* nm        = (const float*)d_in[5];
    const float* mapping   = (const float*)d_in[6];
    const float* samelb    = (const float*)d_in[7];
    const int*   ei        = (const int*)d_in[8];
    const float* W0 = (const float*)d_in[9],  *b0 = (const float*)d_in[10];
    const float* W1 = (const float*)d_in[11], *b1 = (const float*)d_in[12];
    const float* W2 = (const float*)d_in[13], *b2 = (const float*)d_in[14];
    const float* W3 = (const float*)d_in[15], *b3 = (const float*)d_in[16];
    float* out = (float*)d_out;
    float* ws  = (float*)d_ws;

    hipLaunchKernelGGL(k_init,   dim3(33),      dim3(256), 0, stream, ws, out);
    hipLaunchKernelGGL(k_pool,   dim3(B_, 8),   dim3(256), 0, stream, c_hs, c_valid, ws);
    hipLaunchKernelGGL(k_mlp2,   dim3(B_),      dim3(DFC), 0, stream, ws,
                       W0, b0, W1, b1, W2, b2, W3, b3, out);
    hipLaunchKernelGGL(k_rows,   dim3(B_, 32),  dim3(256), 0, stream, attention, ws);
    hipLaunchKernelGGL(k_cols,   dim3(B_, 6),   dim3(256), 0, stream, attention, ws);
    hipLaunchKernelGGL(k_prep,   dim3(12, B_),  dim3(256), 0, stream, attention, ws);
    hipLaunchKernelGGL(k_scan,   dim3(32, B_),  dim3(256), 0, stream, attention, mapping, samelb, ws);
    hipLaunchKernelGGL(k_kabsch, dim3(B_),      dim3(N1_), 0, stream, coords, upd, nm, ei, ws, out);
}

// Round 5
// 387.575 us; speedup vs baseline: 1.4918x; 1.0060x over previous
//
#include <hip/hip_runtime.h>
#include <math.h>

#define B_   128
#define N1_  128
#define N2_  384
#define N_   512
#define E_   1024
#define DIN  64
#define DFC  128

// workspace layout (floats)
#define ACC_TOP  0
#define ACC_BOT  128
#define POOL_OFF 256                          // B*64 = 8192
#define RNI_OFF  (POOL_OFF + B_*DIN)          // 8448:  B*N1 reciprocal rownorms
#define CNI_OFF  (RNI_OFF + B_*N1_)           // 24832: B*N2 reciprocal colnorms
#define BI_OFF   (CNI_OFF + B_*N2_)           // 73984: B*N1 argmax ints
#define EB_OFF   (BI_OFF + B_*N1_)            // 90368: B*384*128 exp-matrix (25 MB)
#define ZERO_CNT (POOL_OFF + B_*DIN)

// ---------------- init ----------------
// grid 33, block 256
__global__ void k_init(float* ws, float* out) {
    int idx = blockIdx.x * 256 + threadIdx.x;
    if (idx < ZERO_CNT) ws[idx] = 0.f;
    if (blockIdx.x == 0 && threadIdx.x < 4) out[128 + threadIdx.x] = 0.f;
}

// ---------------- masked mean-pool ----------------
// grid (B, 8), block 256
__global__ void k_pool(const float* __restrict__ c_hs, const float* __restrict__ c_valid,
                       float* __restrict__ ws) {
    __shared__ float4 sred[256];
    int b = blockIdx.x, t = threadIdx.x;
    int chunk = blockIdx.y * 64;
    int d4 = t & 15, rl = t >> 4;
    const float4* X4 = (const float4*)(c_hs + (size_t)b * N_ * DIN);
    const float* V = c_valid + (size_t)b * N_;
    float4 acc = {0.f, 0.f, 0.f, 0.f};
    #pragma unroll
    for (int r = chunk + rl; r < chunk + 64; r += 16) {
        float4 x = X4[r * 16 + d4];
        float v = V[r];
        acc.x += x.x * v; acc.y += x.y * v; acc.z += x.z * v; acc.w += x.w * v;
    }
    sred[t] = acc; __syncthreads();
    for (int off = 128; off >= 16; off >>= 1) {
        if (t < off) {
            float4 o = sred[t + off];
            sred[t].x += o.x; sred[t].y += o.y; sred[t].z += o.z; sred[t].w += o.w;
        }
        __syncthreads();
    }
    if (t < 16) {
        float4 s = sred[t];
        float* p = ws + POOL_OFF + b * DIN + t * 4;
        atomicAdd(&p[0], s.x); atomicAdd(&p[1], s.y);
        atomicAdd(&p[2], s.z); atomicAdd(&p[3], s.w);
    }
}

// ---------------- scores MLP ----------------
// grid B, block 128
__global__ void k_mlp2(const float* __restrict__ ws,
                       const float* __restrict__ W0, const float* __restrict__ b0,
                       const float* __restrict__ W1, const float* __restrict__ b1,
                       const float* __restrict__ W2, const float* __restrict__ b2,
                       const float* __restrict__ W3, const float* __restrict__ b3,
                       float* __restrict__ out) {
    __shared__ float pool[DIN];
    __shared__ float h[DFC];
    __shared__ float h2[DFC];
    __shared__ float part[DFC];
    int b = blockIdx.x, t = threadIdx.x;
    if (t < DIN) pool[t] = ws[POOL_OFF + b * DIN + t] * (1.0f / 128.0f);
    __syncthreads();
    float a = b0[t];
    #pragma unroll
    for (int i = 0; i < DIN; ++i) a += pool[i] * W0[i * DFC + t];
    h[t] = fmaxf(a, 0.f); __syncthreads();
    a = b1[t];
    #pragma unroll
    for (int i = 0; i < DFC; ++i) a += h[i] * W1[i * DFC + t];
    h2[t] = fmaxf(a, 0.f); __syncthreads();
    a = b2[t];
    #pragma unroll
    for (int i = 0; i < DFC; ++i) a += h2[i] * W2[i * DFC + t];
    part[t] = fmaxf(a, 0.f) * W3[t];
    __syncthreads();
    for (int off = 64; off > 0; off >>= 1) { if (t < off) part[t] += part[t + off]; __syncthreads(); }
    if (t == 0) out[b] = 1.f / (1.f + expf(-(part[0] + b3[0])));
}

// ---------------- per-row: reciprocal rownorm + argmax (one wave per row) ----------------
// grid (B, 32), block 256
__global__ void k_rows(const float* __restrict__ att, float* __restrict__ ws) {
    int b = blockIdx.x, t = threadIdx.x, wv = t >> 6, ln = t & 63;
    int r = blockIdx.y * 4 + wv;
    const float* row = att + ((size_t)b * N1_ + r) * N2_;
    float ssq = 0.f, best = -1e30f; int bidx = 0;
    #pragma unroll
    for (int q = 0; q < 6; ++q) {
        float v = row[ln + 64 * q];
        ssq += v * v;
        if (v > best) { best = v; bidx = ln + 64 * q; }   // ascending: > keeps first
    }
    for (int off = 32; off > 0; off >>= 1) {
        ssq += __shfl_xor(ssq, off, 64);
        float ov = __shfl_xor(best, off, 64);
        int oi = __shfl_xor(bidx, off, 64);
        if (ov > best || (ov == best && oi < bidx)) { best = ov; bidx = oi; }
    }
    if (ln == 0) {
        ws[RNI_OFF + b * N1_ + r] = 1.f / fmaxf(sqrtf(ssq), 1e-12f);
        ((int*)ws)[BI_OFF + b * N1_ + r] = bidx;
    }
}

// ---------------- reciprocal column norms ----------------
// grid (B, 6), block 256: 64 cols/block, 4 row-quarters
__global__ void k_cols(const float* __restrict__ att, float* __restrict__ ws) {
    __shared__ float sred[256];
    int b = blockIdx.x, t = threadIdx.x;
    int c = blockIdx.y * 64 + (t & 63);
    int q = t >> 6;
    const float* A = att + (size_t)b * N1_ * N2_;
    float s = 0.f;
    #pragma unroll 8
    for (int j = q * 32; j < q * 32 + 32; ++j) { float v = A[j * N2_ + c]; s += v * v; }
    sred[t] = s; __syncthreads();
    if (t < 64)
        ws[CNI_OFF + b * N2_ + blockIdx.y * 64 + t] =
            1.f / fmaxf(sqrtf(sred[t] + sred[t + 64] + sred[t + 128] + sred[t + 192]), 1e-12f);
}

// ---------------- prep: eB[r][j] = exp(-att[j,r]*rinv[j]) (transposed) ----------------
// grid (12, B), block 256. Strip of 32 att-cols.
#define TP 129
__global__ void k_prep(const float* __restrict__ att, float* __restrict__ ws) {
    __shared__ float tile[32 * TP];
    __shared__ float rinv[N1_];
    int b = blockIdx.y, t = threadIdx.x;
    int r0 = blockIdx.x * 32;
    if (t < N1_) rinv[t] = ws[RNI_OFF + b * N1_ + t];
    __syncthreads();
    const float4* att4 = (const float4*)(att + (size_t)b * N1_ * N2_);
    int c8 = t & 7, jb = t >> 3;                 // 32 rows per pass
    #pragma unroll
    for (int p = 0; p < 4; ++p) {
        int j = jb + p * 32;
        float4 a = att4[j * 96 + blockIdx.x * 8 + c8];
        float rv = rinv[j];
        tile[(c8 * 4 + 0) * TP + j] = a.x * rv;
        tile[(c8 * 4 + 1) * TP + j] = a.y * rv;
        tile[(c8 * 4 + 2) * TP + j] = a.z * rv;
        tile[(c8 * 4 + 3) * TP + j] = a.w * rv;
    }
    __syncthreads();
    int j4 = t & 31, cb = t >> 5;                // 8 eB-rows per pass
    float4* eb4 = (float4*)(ws + EB_OFF + ((size_t)b * N2_ + r0) * N1_);
    #pragma unroll
    for (int p = 0; p < 4; ++p) {
        int c = cb + p * 8;
        float4 e;
        e.x = __expf(-tile[c * TP + j4 * 4]);
        e.y = __expf(-tile[c * TP + j4 * 4 + 1]);
        e.z = __expf(-tile[c * TP + j4 * 4 + 2]);
        e.w = __expf(-tile[c * TP + j4 * 4 + 3]);
        eb4[c * 32 + j4] = e;
    }
}

// ---------------- fused mask scan: all 512 rows, 16 rows/block ----------------
// grid (32, B), block 256. Loads batched into registers for MLP.
__global__ __launch_bounds__(256, 2)
void k_scan(const float* __restrict__ att, const float* __restrict__ mapping,
            const float* __restrict__ samelb, float* __restrict__ ws) {
    __shared__ float cninv[N2_];
    __shared__ float rt[4], rb[4];
    int b = blockIdx.y, t = threadIdx.x;
    int i0 = blockIdx.x * 16;
    const float4* m4 = (const float4*)(mapping + ((size_t)b * N_ + i0) * N_);
    const float4* s4 = (const float4*)(samelb + ((size_t)b * N_ + i0) * N_);
    float top = 0.f, bot = 0.f;
    if (i0 < N1_) {
        // type A: rows [0,128). cols<128: count (atten==0 -> e=1); cols>=128: exp(-att*cninv)
        for (int j = t; j < N2_; j += 256) cninv[j] = ws[CNI_OFF + b * N2_ + j];
        __syncthreads();
        const float4* a4 = (const float4*)(att + ((size_t)b * N1_ + i0) * N2_);
        float4 md[2], sd[2], av[6], mv[6], sv[6];
        int ri[6], ci[6];
        #pragma unroll
        for (int k = 0; k < 2; ++k) { int g = t + k * 256; md[k] = m4[(g >> 5) * 128 + (g & 31)]; }
        #pragma unroll
        for (int k = 0; k < 2; ++k) { int g = t + k * 256; sd[k] = s4[(g >> 5) * 128 + (g & 31)]; }
        #pragma unroll
        for (int k = 0; k < 6; ++k) {
            int g = t + k * 256; ri[k] = g / 96; ci[k] = g - ri[k] * 96;
            av[k] = a4[ri[k] * 96 + ci[k]];
        }
        #pragma unroll
        for (int k = 0; k < 6; ++k) mv[k] = m4[ri[k] * 128 + 32 + ci[k]];
        #pragma unroll
        for (int k = 0; k < 6; ++k) sv[k] = s4[ri[k] * 128 + 32 + ci[k]];
        #pragma unroll
        for (int k = 0; k < 2; ++k) {
            top += md[k].x + md[k].y + md[k].z + md[k].w;
            bot += sd[k].x + sd[k].y + sd[k].z + sd[k].w;
        }
        #pragma unroll
        for (int k = 0; k < 6; ++k) {
            int cb = ci[k] * 4;
            float e0 = __expf(-av[k].x * cninv[cb]);
            float e1 = __expf(-av[k].y * cninv[cb + 1]);
            float e2 = __expf(-av[k].z * cninv[cb + 2]);
            float e3 = __expf(-av[k].w * cninv[cb + 3]);
            top += mv[k].x * e0 + mv[k].y * e1 + mv[k].z * e2 + mv[k].w * e3;
            bot += sv[k].x * e0 + sv[k].y * e1 + sv[k].z * e2 + sv[k].w * e3;
        }
    } else {
        // type B: rows [128,512). cols<128: e from precomputed eB; cols>=128: count
        const float4* eb4 = (const float4*)(ws + EB_OFF + ((size_t)b * N2_ + (i0 - N1_)) * N1_);
        float4 ev[2], mv[2], sv[2], mc[6], sc[6];
        #pragma unroll
        for (int k = 0; k < 2; ++k) { int g = t + k * 256; ev[k] = eb4[(g >> 5) * 32 + (g & 31)]; }
        #pragma unroll
        for (int k = 0; k < 2; ++k) { int g = t + k * 256; mv[k] = m4[(g >> 5) * 128 + (g & 31)]; }
        #pragma unroll
        for (int k = 0; k < 2; ++k) { int g = t + k * 256; sv[k] = s4[(g >> 5) * 128 + (g & 31)]; }
        #pragma unroll
        for (int k = 0; k < 6; ++k) {
            int g = t + k * 256; int r = g / 96, c = g - r * 96;
            mc[k] = m4[r * 128 + 32 + c];
        }
        #pragma unroll
        for (int k = 0; k < 6; ++k) {
            int g = t + k * 256; int r = g / 96, c = g - r * 96;
            sc[k] = s4[r * 128 + 32 + c];
        }
        #pragma unroll
        for (int k = 0; k < 2; ++k) {
            top += mv[k].x * ev[k].x + mv[k].y * ev[k].y + mv[k].z * ev[k].z + mv[k].w * ev[k].w;
            bot += sv[k].x * ev[k].x + sv[k].y * ev[k].y + sv[k].z * ev[k].z + sv[k].w * ev[k].w;
        }
        #pragma unroll
        for (int k = 0; k < 6; ++k) {
            top += mc[k].x + mc[k].y + mc[k].z + mc[k].w;
            bot += sc[k].x + sc[k].y + sc[k].z + sc[k].w;
        }
    }
    for (int off = 32; off > 0; off >>= 1) {
        top += __shfl_down(top, off, 64);
        bot += __shfl_down(bot, off, 64);
    }
    int wv = t >> 6, ln = t & 63;
    if (ln == 0) { rt[wv] = top; rb[wv] = bot; }
    __syncthreads();
    if (t == 0) {
        atomicAdd(&ws[ACC_TOP + b], rt[0] + rt[1] + rt[2] + rt[3]);
        atomicAdd(&ws[ACC_BOT + b], rb[0] + rb[1] + rb[2] + rb[3]);
    }
}

// ---------------- Kabsch + pairdst + attn finalize ----------------
// block = 128 (2 waves): shuffle-based block reduction
__device__ inline float bred(float* s2, float v, int t) {
    for (int off = 32; off > 0; off >>= 1) v += __shfl_down(v, off, 64);
    if ((t & 63) == 0) s2[t >> 6] = v;
    __syncthreads();
    float r = s2[0] + s2[1];
    __syncthreads();
    return r;
}

// grid B, block 128
__global__ void k_kabsch(const float* __restrict__ coords, const float* __restrict__ upd,
                         const float* __restrict__ nm, const int* __restrict__ ei,
                         const float* __restrict__ ws, float* __restrict__ out) {
    __shared__ float s2[2];
    __shared__ float Rsh[9], Tsh[3];
    int b = blockIdx.x, t = threadIdx.x;
    int bidx = ((const int*)ws)[BI_OFF + b * N1_ + t];
    float P[3], Q[3];
    const float* up = upd + ((size_t)b * N_ + t) * 3;
    P[0] = up[0]; P[1] = up[1]; P[2] = up[2];
    const float* qp = coords + ((size_t)b * N_ + N1_ + bidx) * 3;
    Q[0] = qp[0]; Q[1] = qp[1]; Q[2] = qp[2];
    float Pm[3], Qm[3];
    for (int a = 0; a < 3; ++a) Pm[a] = bred(s2, P[a], t) * (1.f / 128.f);
    for (int a = 0; a < 3; ++a) Qm[a] = bred(s2, Q[a], t) * (1.f / 128.f);
    float H[9];
    for (int a = 0; a < 3; ++a)
        for (int c = 0; c < 3; ++c)
            H[a * 3 + c] = bred(s2, (P[a] - Pm[a]) * (Q[c] - Qm[c]), t) * (1.f / 8.f);
    if (t == 0) {
        double Hd[3][3];
        for (int a = 0; a < 3; ++a) for (int c = 0; c < 3; ++c) Hd[a][c] = (double)H[a * 3 + c];
        double A[3][3], V[3][3] = {{1,0,0},{0,1,0},{0,0,1}};
        for (int i = 0; i < 3; ++i)
            for (int j = 0; j < 3; ++j) {
                double z = 0; for (int c = 0; c < 3; ++c) z += Hd[c][i] * Hd[c][j];
                A[i][j] = z;
            }
        for (int sweep = 0; sweep < 8; ++sweep) {
            const int PQ[3][2] = {{0,1},{0,2},{1,2}};
            for (int r = 0; r < 3; ++r) {
                int p = PQ[r][0], q = PQ[r][1];
                double apq = A[p][q];
                if (fabs(apq) < 1e-300) continue;
                double tau = (A[q][q] - A[p][p]) / (2.0 * apq);
                double tt = (tau >= 0 ? 1.0 : -1.0) / (fabs(tau) + sqrt(1.0 + tau * tau));
                double c = 1.0 / sqrt(1.0 + tt * tt), s = tt * c;
                for (int k = 0; k < 3; ++k) { double akp = A[k][p], akq = A[k][q]; A[k][p] = c * akp - s * akq; A[k][q] = s * akp + c * akq; }
                for (int k = 0; k < 3; ++k) { double apk = A[p][k], aqk = A[q][k]; A[p][k] = c * apk - s * aqk; A[q][k] = s * apk + c * aqk; }
                for (int k = 0; k < 3; ++k) { double vkp = V[k][p], vkq = V[k][q]; V[k][p] = c * vkp - s * vkq; V[k][q] = s * vkp + c * vkq; }
            }
        }
        double lam[3] = {A[0][0], A[1][1], A[2][2]};
        int id[3] = {0, 1, 2};
        if (lam[id[0]] < lam[id[1]]) { int x = id[0]; id[0] = id[1]; id[1] = x; }
        if (lam[id[0]] < lam[id[2]]) { int x = id[0]; id[0] = id[2]; id[2] = x; }
        if (lam[id[1]] < lam[id[2]]) { int x = id[1]; id[1] = id[2]; id[2] = x; }
        double u[3][3], v[3][3], sv[3];
        for (int i = 0; i < 3; ++i) {
            for (int k = 0; k < 3; ++k) v[i][k] = V[k][id[i]];
            double uv[3];
            for (int c = 0; c < 3; ++c) uv[c] = Hd[c][0] * v[i][0] + Hd[c][1] * v[i][1] + Hd[c][2] * v[i][2];
            double n = sqrt(uv[0] * uv[0] + uv[1] * uv[1] + uv[2] * uv[2]);
            sv[i] = n;
            if (n > 1e-150) { u[i][0] = uv[0] / n; u[i][1] = uv[1] / n; u[i][2] = uv[2] / n; }
            else { u[i][0] = u[i][1] = u[i][2] = 0.0; }
        }
        if (sv[2] < 1e-12 * fmax(sv[0], 1e-300)) {
            u[2][0] = u[0][1] * u[1][2] - u[0][2] * u[1][1];
            u[2][1] = u[0][2] * u[1][0] - u[0][0] * u[1][2];
            u[2][2] = u[0][0] * u[1][1] - u[0][1] * u[1][0];
        }
        double det = Hd[0][0] * (Hd[1][1] * Hd[2][2] - Hd[1][2] * Hd[2][1])
                   - Hd[0][1] * (Hd[1][0] * Hd[2][2] - Hd[1][2] * Hd[2][0])
                   + Hd[0][2] * (Hd[1][0] * Hd[2][1] - Hd[1][1] * Hd[2][0]);
        double dsg = (det > 0.0) ? 1.0 : ((det < 0.0) ? -1.0 : 0.0);
        for (int a = 0; a < 3; ++a)
            for (int c = 0; c < 3; ++c)
                Rsh[a * 3 + c] = (float)(u[0][a] * v[0][c] + u[1][a] * v[1][c] + dsg * u[2][a] * v[2][c]);
        for (int a = 0; a < 3; ++a)
            Tsh[a] = Qm[a] - (Rsh[a * 3] * Pm[0] + Rsh[a * 3 + 1] * Pm[1] + Rsh[a * 3 + 2] * Pm[2]);
    }
    __syncthreads();
    float Pp[3];
    for (int a = 0; a < 3; ++a)
        Pp[a] = Rsh[a * 3] * P[0] + Rsh[a * 3 + 1] * P[1] + Rsh[a * 3 + 2] * P[2] + Tsh[a];
    float mk = (nm[b * N1_ + t] > 0.5f) ? 1.f : 0.f;
    float dx = Pp[0] - Q[0], dy = Pp[1] - Q[1], dz = Pp[2] - Q[2];
    float rsum = bred(s2, mk * (dx * dx + dy * dy + dz * dz), t);
    float msum = bred(s2, mk, t);
    float Ppm[3];
    for (int a = 0; a < 3; ++a) Ppm[a] = bred(s2, Pp[a], t) * (1.f / 128.f);
    if (t == 0) {
        float cnt = fmaxf(msum * 3.f, 1.f);
        atomicAdd(&out[129], (rsum / cnt) * (1.f / 128.f));
        float cen = 0.f;
        for (int a = 0; a < 3; ++a) { float d2 = Ppm[a] - Qm[a]; cen += d2 * d2; }
        atomicAdd(&out[131], (cen / 3.f) * (1.f / 128.f));
    }
    // ---- fused pairdst ----
    const float* C = coords + (size_t)b * N_ * 3;
    const float* U = upd + (size_t)b * N_ * 3;
    const int* e = ei + (size_t)b * E_ * 2;
    float acc = 0.f;
    for (int idx = t; idx < E_; idx += 128) {
        int a0 = e[idx * 2], a1 = e[idx * 2 + 1];
        float ex = C[a0 * 3] - C[a1 * 3], ey = C[a0 * 3 + 1] - C[a1 * 3 + 1], ez = C[a0 * 3 + 2] - C[a1 * 3 + 2];
        float d0 = sqrtf(ex * ex + ey * ey + ez * ez + 1e-12f);
        ex = U[a0 * 3] - U[a1 * 3]; ey = U[a0 * 3 + 1] - U[a1 * 3 + 1]; ez = U[a0 * 3 + 2] - U[a1 * 3 + 2];
        float d1 = sqrtf(ex * ex + ey * ey + ez * ez + 1e-12f);
        acc += d1 - d0;
    }
    float psum = bred(s2, acc, t);
    if (t == 0) atomicAdd(&out[130], fabsf(psum) * (1.f / 128.f));
    // ---- fused attn_loss finalize ----
    if (b == 0) {
        float top = ws[ACC_TOP + t], bot = ws[ACC_BOT + t];
        float v = top / (bot - top + 1.0f);
        float s = bred(s2, v, t);
        if (t == 0) out[128] = s * (1.0f / 128.0f);
    }
}

extern "C" void kernel_launch(void* const* d_in, const int* in_sizes, int n_in,
                              void* d_out, int out_size, void* d_ws, size_t ws_size,
                              hipStream_t stream) {
    const float* c_hs      = (const float*)d_in[0];
    const float* attention = (const float*)d_in[1];
    const float* coords    = (const float*)d_in[2];
    const float* upd       = (const float*)d_in[3];
    const float* c_valid   = (const float*)d_in[4];
    const float* nm        = (const float*)d_in[5];
    const float* mapping   = (const float*)d_in[6];
    const float* samelb    = (const float*)d_in[7];
    const int*   ei        = (const int*)d_in[8];
    const float* W0 = (const float*)d_in[9],  *b0 = (const float*)d_in[10];
    const float* W1 = (const float*)d_in[11], *b1 = (const float*)d_in[12];
    const float* W2 = (const float*)d_in[13], *b2 = (const float*)d_in[14];
    const float* W3 = (const float*)d_in[15], *b3 = (const float*)d_in[16];
    float* out = (float*)d_out;
    float* ws  = (float*)d_ws;

    hipLaunchKernelGGL(k_init,   dim3(33),      dim3(256), 0, stream, ws, out);
    hipLaunchKernelGGL(k_pool,   dim3(B_, 8),   dim3(256), 0, stream, c_hs, c_valid, ws);
    hipLaunchKernelGGL(k_mlp2,   dim3(B_),      dim3(DFC), 0, stream, ws,
                       W0, b0, W1, b1, W2, b2, W3, b3, out);
    hipLaunchKernelGGL(k_rows,   dim3(B_, 32),  dim3(256), 0, stream, attention, ws);
    hipLaunchKernelGGL(k_cols,   dim3(B_, 6),   dim3(256), 0, stream, attention, ws);
    hipLaunchKernelGGL(k_prep,   dim3(12, B_),  dim3(256), 0, stream, attention, ws);
    hipLaunchKernelGGL(k_scan,   dim3(32, B_),  dim3(256), 0, stream, attention, mapping, samelb, ws);
    hipLaunchKernelGGL(k_kabsch, dim3(B_),      dim3(N1_), 0, stream, coords, upd, nm, ei, ws, out);
}